// Round 1
// baseline (361.057 us; speedup 1.0000x reference)
//
#include <hip/hip_runtime.h>
#include <hip/hip_bf16.h>

#define N_NODES 20000
#define N_EDGES 640000
#define HID 128
#define HEADS 8
#define HD 16

// ---------------------------------------------------------------- utilities

__global__ void zero_int_kernel(int* __restrict__ p, int n) {
    int i = blockIdx.x * 256 + threadIdx.x;
    if (i < n) p[i] = 0;
}

__global__ void hist_kernel(const int* __restrict__ src, int* __restrict__ cnt) {
    int e = blockIdx.x * 256 + threadIdx.x;
    if (e < N_EDGES) atomicAdd(&cnt[src[e]], 1);
}

// single-block exclusive scan over cnt[0..n) -> start[0..n], start[n]=total
__global__ void scan_kernel(const int* __restrict__ cnt, int* __restrict__ start, int n) {
    __shared__ int sdata[1024];
    __shared__ int carry;
    const int tid = threadIdx.x;
    if (tid == 0) carry = 0;
    __syncthreads();
    for (int base = 0; base < n; base += 1024) {
        int i = base + tid;
        int x = (i < n) ? cnt[i] : 0;
        sdata[tid] = x;
        __syncthreads();
        for (int off = 1; off < 1024; off <<= 1) {
            int t = (tid >= off) ? sdata[tid - off] : 0;
            __syncthreads();
            sdata[tid] += t;
            __syncthreads();
        }
        if (i < n) start[i] = carry + sdata[tid] - x;
        int total = sdata[1023];
        __syncthreads();
        if (tid == 0) carry += total;
        __syncthreads();
    }
    if (tid == 0) start[n] = carry;
}

// scatter edges into src-sorted order; pre-bake the 6 edge-bias heads
__global__ void scatter_kernel(const int* __restrict__ src, const int* __restrict__ dst,
                               const float* __restrict__ dist, const float* __restrict__ bpp,
                               const float* __restrict__ msa, const float* __restrict__ chem,
                               const float* __restrict__ rel, const float* __restrict__ chain,
                               const float* __restrict__ w_dist, const float* __restrict__ b_dist,
                               const float* __restrict__ w_bpp, const float* __restrict__ b_bpp,
                               const float* __restrict__ w_msa, const float* __restrict__ b_msa,
                               const float* __restrict__ w_chem, const float* __restrict__ b_chem,
                               const float* __restrict__ w_rel, const float* __restrict__ b_rel,
                               const float* __restrict__ w_chain, const float* __restrict__ b_chain,
                               const int* __restrict__ start, int* __restrict__ cnt,
                               int* __restrict__ dstS, float* __restrict__ biasS) {
    int e = blockIdx.x * 256 + threadIdx.x;
    if (e >= N_EDGES) return;
    int s = src[e];
    int pos = start[s] + atomicAdd(&cnt[s], 1);
    dstS[pos] = dst[e];
    float d2 = dist[e] * dist[e];
    float f_bpp = bpp[e], f_msa = msa[e], f_chem = chem[e], f_rel = rel[e], f_chain = chain[e];
    float out[8];
#pragma unroll
    for (int h = 0; h < 8; ++h) {
        float b = -(d2 * w_dist[h] + b_dist[h])
                + (f_bpp * w_bpp[h] + b_bpp[h])
                + (f_msa * w_msa[h] + b_msa[h])
                + (f_chem * w_chem[h] + b_chem[h])
                + (f_rel * w_rel[h] + b_rel[h])
                + (f_chain * w_chain[h] + b_chain[h]);
        out[h] = b;
    }
    float4* bp = reinterpret_cast<float4*>(&biasS[(size_t)pos * 8]);
    bp[0] = make_float4(out[0], out[1], out[2], out[3]);
    bp[1] = make_float4(out[4], out[5], out[6], out[7]);
}

// ------------------------------------------------------------- q,k,v GEMMs
// block: 256 threads, 16 rows; each thread: 1 column x 8 rows per group
__global__ __launch_bounds__(256) void qkv_kernel(const float* __restrict__ h,
        const float* __restrict__ Wq, const float* __restrict__ Wk, const float* __restrict__ Wv,
        const float* __restrict__ bq, const float* __restrict__ bk, const float* __restrict__ bv,
        float* __restrict__ q, float* __restrict__ k, float* __restrict__ v) {
    __shared__ float hs[16 * 128];
    const int tid = threadIdx.x;
    const int row0 = blockIdx.x * 16;
    for (int i = tid; i < 16 * 128; i += 256) hs[i] = h[(size_t)row0 * 128 + i];
    __syncthreads();
    const int c = tid & 127;
    const int g = tid >> 7;   // 0 or 1
    const float* Ws[3] = {Wq, Wk, Wv};
    const float* bs[3] = {bq, bk, bv};
    float* outs[3] = {q, k, v};
#pragma unroll
    for (int mtx = 0; mtx < 3; ++mtx) {
        const float* W = Ws[mtx];
        float acc[8];
#pragma unroll
        for (int r = 0; r < 8; ++r) acc[r] = 0.f;
        for (int kk = 0; kk < 128; kk += 4) {
            float w0 = W[(kk + 0) * 128 + c];
            float w1 = W[(kk + 1) * 128 + c];
            float w2 = W[(kk + 2) * 128 + c];
            float w3 = W[(kk + 3) * 128 + c];
#pragma unroll
            for (int r = 0; r < 8; ++r) {
                const float4 hv = *reinterpret_cast<const float4*>(&hs[(g * 8 + r) * 128 + kk]);
                acc[r] += hv.x * w0 + hv.y * w1 + hv.z * w2 + hv.w * w3;
            }
        }
        float bias = bs[mtx][c];
        float* out = outs[mtx];
#pragma unroll
        for (int r = 0; r < 8; ++r) out[(size_t)(row0 + g * 8 + r) * 128 + c] = acc[r] + bias;
    }
}

// --------------------------------------------- per-node fused softmax + agg
// one block (128 threads) per node; thread t = head(t>>4) * 16 + dim(t&15)
__global__ __launch_bounds__(128) void node_kernel(const float* __restrict__ q,
        const float* __restrict__ k, const float* __restrict__ v,
        const float* __restrict__ x, const float* __restrict__ biasS,
        const int* __restrict__ dstS, const int* __restrict__ start,
        float* __restrict__ h_update, float* __restrict__ disp) {
    const int n = blockIdx.x;
    const int t = threadIdx.x;
    const int hh = t >> 4;
    const int d = t & 15;
    const int s0 = start[n];
    const int s1 = start[n + 1];
    const float qv = q[(size_t)n * 128 + t];
    const float xs = (d < 3) ? x[(size_t)n * 3 + d] : 0.f;
    float m = -INFINITY, denom = 0.f, acc = 0.f, accD = 0.f;
    for (int p = s0; p < s1; ++p) {
        int dn = dstS[p];
        float kv = k[(size_t)dn * 128 + t];
        float lp = qv * kv;
        lp += __shfl_xor(lp, 1);
        lp += __shfl_xor(lp, 2);
        lp += __shfl_xor(lp, 4);
        lp += __shfl_xor(lp, 8);
        float l = lp * 0.25f + biasS[(size_t)p * 8 + hh];
        float nm = fmaxf(m, l);
        float corr = __expf(m - nm);     // exp(-inf) = 0 handles first edge
        float pe = __expf(l - nm);
        denom = denom * corr + pe;
        float vv = v[(size_t)dn * 128 + t];
        acc = acc * corr + pe * vv;
        if (d < 3) accD = accD * corr + pe * (x[(size_t)dn * 3 + d] - xs);
        m = nm;
    }
    float w = 1.0f / fmaxf(denom, 1e-9f);
    h_update[(size_t)n * 128 + t] = acc * w;
    __shared__ float sd[8][3];
    if (d < 3) sd[hh][d] = accD * w * 0.125f;
    __syncthreads();
    if (t < 3) {
        float s = 0.f;
#pragma unroll
        for (int i = 0; i < 8; ++i) s += sd[i][t];
        disp[(size_t)n * 3 + t] = s;
    }
}

// ------------------------------------- fused output GEMM + gate MLP + coords
__global__ __launch_bounds__(256) void out_kernel(const float* __restrict__ h,
        const float* __restrict__ x, const float* __restrict__ hu,
        const float* __restrict__ Wo, const float* __restrict__ bo,
        const float* __restrict__ Wg1, const float* __restrict__ bg1,
        const float* __restrict__ wg2, const float* __restrict__ bg2,
        const float* __restrict__ disp,
        float* __restrict__ hout, float* __restrict__ xout) {
    __shared__ float bufA[16 * 128];
    __shared__ float bufB[16 * 128];
    const int tid = threadIdx.x;
    const int row0 = blockIdx.x * 16;
    for (int i = tid; i < 16 * 128; i += 256) bufA[i] = hu[(size_t)row0 * 128 + i];
    __syncthreads();
    const int c = tid & 127;
    const int g = tid >> 7;
    float acc[8];
#pragma unroll
    for (int r = 0; r < 8; ++r) acc[r] = 0.f;
    for (int kk = 0; kk < 128; kk += 4) {
        float w0 = Wo[(kk + 0) * 128 + c];
        float w1 = Wo[(kk + 1) * 128 + c];
        float w2 = Wo[(kk + 2) * 128 + c];
        float w3 = Wo[(kk + 3) * 128 + c];
#pragma unroll
        for (int r = 0; r < 8; ++r) {
            const float4 hv = *reinterpret_cast<const float4*>(&bufA[(g * 8 + r) * 128 + kk]);
            acc[r] += hv.x * w0 + hv.y * w1 + hv.z * w2 + hv.w * w3;
        }
    }
    float bov = bo[c];
#pragma unroll
    for (int r = 0; r < 8; ++r) {
        int row = row0 + g * 8 + r;
        float ho = h[(size_t)row * 128 + c] + acc[r] + bov;
        hout[(size_t)row * 128 + c] = ho;
        bufB[(g * 8 + r) * 128 + c] = ho;
    }
    __syncthreads();
    // stage 2: g1 = silu(h_out @ Wg1 + bg1)
#pragma unroll
    for (int r = 0; r < 8; ++r) acc[r] = 0.f;
    for (int kk = 0; kk < 128; kk += 4) {
        float w0 = Wg1[(kk + 0) * 128 + c];
        float w1 = Wg1[(kk + 1) * 128 + c];
        float w2 = Wg1[(kk + 2) * 128 + c];
        float w3 = Wg1[(kk + 3) * 128 + c];
#pragma unroll
        for (int r = 0; r < 8; ++r) {
            const float4 hv = *reinterpret_cast<const float4*>(&bufB[(g * 8 + r) * 128 + kk]);
            acc[r] += hv.x * w0 + hv.y * w1 + hv.z * w2 + hv.w * w3;
        }
    }
    float bg1v = bg1[c];
#pragma unroll
    for (int r = 0; r < 8; ++r) {
        float a = acc[r] + bg1v;
        float s = a / (1.f + __expf(-a));   // silu
        bufA[(g * 8 + r) * 128 + c] = s;
    }
    __syncthreads();
    // gate = tanh(g1 @ wg2 + bg2); x_out = x + gate * disp
    {
        int r = tid >> 4, j = tid & 15;
        float partial = 0.f;
        for (int cc = j; cc < 128; cc += 16) partial += bufA[r * 128 + cc] * wg2[cc];
        partial += __shfl_xor(partial, 1);
        partial += __shfl_xor(partial, 2);
        partial += __shfl_xor(partial, 4);
        partial += __shfl_xor(partial, 8);
        float gate = tanhf(partial + bg2[0]);
        if (j < 3) {
            int row = row0 + r;
            xout[(size_t)row * 3 + j] = x[(size_t)row * 3 + j] + gate * disp[(size_t)row * 3 + j];
        }
    }
}

// ---------------------------------------------------------------- launcher

extern "C" void kernel_launch(void* const* d_in, const int* in_sizes, int n_in,
                              void* d_out, int out_size, void* d_ws, size_t ws_size,
                              hipStream_t stream) {
    const float* h     = (const float*)d_in[0];
    const float* x     = (const float*)d_in[1];
    const int*   src   = (const int*)d_in[2];
    const int*   dst   = (const int*)d_in[3];
    const float* dist  = (const float*)d_in[4];
    const float* bpp   = (const float*)d_in[5];
    const float* msa   = (const float*)d_in[6];
    const float* chem  = (const float*)d_in[7];
    const float* rel   = (const float*)d_in[8];
    const float* chain = (const float*)d_in[9];
    const float* Wq = (const float*)d_in[10];
    const float* Wk = (const float*)d_in[11];
    const float* Wv = (const float*)d_in[12];
    const float* Wo = (const float*)d_in[13];
    const float* bq = (const float*)d_in[14];
    const float* bk = (const float*)d_in[15];
    const float* bv = (const float*)d_in[16];
    const float* bo = (const float*)d_in[17];
    const float* w_dist = (const float*)d_in[18];  const float* b_dist = (const float*)d_in[19];
    const float* w_bpp  = (const float*)d_in[20];  const float* b_bpp  = (const float*)d_in[21];
    const float* w_msa  = (const float*)d_in[22];  const float* b_msa  = (const float*)d_in[23];
    const float* w_chem = (const float*)d_in[24];  const float* b_chem = (const float*)d_in[25];
    const float* w_rel  = (const float*)d_in[26];  const float* b_rel  = (const float*)d_in[27];
    const float* w_chain= (const float*)d_in[28];  const float* b_chain= (const float*)d_in[29];
    const float* Wg1 = (const float*)d_in[30];
    const float* bg1 = (const float*)d_in[31];
    const float* wg2 = (const float*)d_in[32];
    const float* bg2 = (const float*)d_in[33];

    float* fws   = (float*)d_ws;
    float* q     = fws;                           // N*128
    float* k     = q + (size_t)N_NODES * HID;     // N*128
    float* v     = k + (size_t)N_NODES * HID;     // N*128
    float* hu    = v + (size_t)N_NODES * HID;     // N*128
    float* biasS = hu + (size_t)N_NODES * HID;    // E*8
    float* disp  = biasS + (size_t)N_EDGES * 8;   // N*3
    int* dstS    = (int*)(disp + (size_t)N_NODES * 3);  // E
    int* startp  = dstS + N_EDGES;                // N+1
    int* cnt     = startp + (N_NODES + 1);        // N

    float* hout = (float*)d_out;
    float* xout = hout + (size_t)N_NODES * HID;

    hipLaunchKernelGGL(zero_int_kernel, dim3((N_NODES + 255) / 256), dim3(256), 0, stream,
                       cnt, N_NODES);
    hipLaunchKernelGGL(hist_kernel, dim3(N_EDGES / 256), dim3(256), 0, stream, src, cnt);
    hipLaunchKernelGGL(scan_kernel, dim3(1), dim3(1024), 0, stream, cnt, startp, N_NODES);
    hipLaunchKernelGGL(zero_int_kernel, dim3((N_NODES + 255) / 256), dim3(256), 0, stream,
                       cnt, N_NODES);
    hipLaunchKernelGGL(scatter_kernel, dim3(N_EDGES / 256), dim3(256), 0, stream,
                       src, dst, dist, bpp, msa, chem, rel, chain,
                       w_dist, b_dist, w_bpp, b_bpp, w_msa, b_msa,
                       w_chem, b_chem, w_rel, b_rel, w_chain, b_chain,
                       startp, cnt, dstS, biasS);
    hipLaunchKernelGGL(qkv_kernel, dim3(N_NODES / 16), dim3(256), 0, stream,
                       h, Wq, Wk, Wv, bq, bk, bv, q, k, v);
    hipLaunchKernelGGL(node_kernel, dim3(N_NODES), dim3(128), 0, stream,
                       q, k, v, x, biasS, dstS, startp, hu, disp);
    hipLaunchKernelGGL(out_kernel, dim3(N_NODES / 16), dim3(256), 0, stream,
                       h, x, hu, Wo, bo, Wg1, bg1, wg2, bg2, disp, hout, xout);
}

// Round 2
// 288.298 us; speedup vs baseline: 1.2524x; 1.2524x over previous
//
#include <hip/hip_runtime.h>
#include <hip/hip_bf16.h>

#define N_NODES 20000
#define N_EDGES 640000
#define HID 128
#define HEADS 8
#define HD 16
#define NB_SCAN ((N_NODES + 255) / 256)   // 79
#define CH 128                            // max edges per softmax chunk

// ---------------------------------------------------------------- utilities

__global__ void zero_int_kernel(int* __restrict__ p, int n) {
    int i = blockIdx.x * 256 + threadIdx.x;
    if (i < n) p[i] = 0;
}

__global__ void hist_kernel(const int* __restrict__ src, int* __restrict__ cnt) {
    int e = blockIdx.x * 256 + threadIdx.x;
    if (e < N_EDGES) atomicAdd(&cnt[src[e]], 1);
}

// ---- hierarchical scan: local block scans -> scan of block sums -> add ----
__global__ __launch_bounds__(256) void scan1_kernel(const int* __restrict__ cnt,
        int* __restrict__ startp, int* __restrict__ blockSums, int n) {
    __shared__ int sd[256];
    const int tid = threadIdx.x;
    const int i = blockIdx.x * 256 + tid;
    int xv = (i < n) ? cnt[i] : 0;
    sd[tid] = xv;
    __syncthreads();
#pragma unroll
    for (int off = 1; off < 256; off <<= 1) {
        int tv = (tid >= off) ? sd[tid - off] : 0;
        __syncthreads();
        sd[tid] += tv;
        __syncthreads();
    }
    if (i < n) startp[i] = sd[tid] - xv;       // local exclusive
    if (tid == 255) blockSums[blockIdx.x] = sd[255];
}

__global__ __launch_bounds__(128) void scan2_kernel(int* __restrict__ blockSums, int nb) {
    __shared__ int sd[128];
    const int tid = threadIdx.x;
    int xv = (tid < nb) ? blockSums[tid] : 0;
    sd[tid] = xv;
    __syncthreads();
#pragma unroll
    for (int off = 1; off < 128; off <<= 1) {
        int tv = (tid >= off) ? sd[tid - off] : 0;
        __syncthreads();
        sd[tid] += tv;
        __syncthreads();
    }
    if (tid < nb) blockSums[tid] = sd[tid] - xv;   // exclusive
    if (tid == 127) blockSums[nb] = sd[127];       // total
}

__global__ void scan3_kernel(int* __restrict__ startp, const int* __restrict__ blockSums,
                             int n, int nb) {
    const int i = blockIdx.x * 256 + threadIdx.x;
    if (i < n) startp[i] += blockSums[blockIdx.x];
    if (i == 0) startp[n] = blockSums[nb];
}

// scatter edges into src-sorted order; pre-bake the 6 edge-bias heads
__global__ void scatter_kernel(const int* __restrict__ src, const int* __restrict__ dst,
                               const float* __restrict__ dist, const float* __restrict__ bpp,
                               const float* __restrict__ msa, const float* __restrict__ chem,
                               const float* __restrict__ rel, const float* __restrict__ chain,
                               const float* __restrict__ w_dist, const float* __restrict__ b_dist,
                               const float* __restrict__ w_bpp, const float* __restrict__ b_bpp,
                               const float* __restrict__ w_msa, const float* __restrict__ b_msa,
                               const float* __restrict__ w_chem, const float* __restrict__ b_chem,
                               const float* __restrict__ w_rel, const float* __restrict__ b_rel,
                               const float* __restrict__ w_chain, const float* __restrict__ b_chain,
                               const int* __restrict__ start, int* __restrict__ cnt,
                               int* __restrict__ dstS, float* __restrict__ biasS) {
    int e = blockIdx.x * 256 + threadIdx.x;
    if (e >= N_EDGES) return;
    int s = src[e];
    int pos = start[s] + atomicAdd(&cnt[s], 1);
    dstS[pos] = dst[e];
    float d2 = dist[e] * dist[e];
    float f_bpp = bpp[e], f_msa = msa[e], f_chem = chem[e], f_rel = rel[e], f_chain = chain[e];
    float out[8];
#pragma unroll
    for (int h = 0; h < 8; ++h) {
        float b = -(d2 * w_dist[h] + b_dist[h])
                + (f_bpp * w_bpp[h] + b_bpp[h])
                + (f_msa * w_msa[h] + b_msa[h])
                + (f_chem * w_chem[h] + b_chem[h])
                + (f_rel * w_rel[h] + b_rel[h])
                + (f_chain * w_chain[h] + b_chain[h]);
        out[h] = b;
    }
    float4* bp = reinterpret_cast<float4*>(&biasS[(size_t)pos * 8]);
    bp[0] = make_float4(out[0], out[1], out[2], out[3]);
    bp[1] = make_float4(out[4], out[5], out[6], out[7]);
}

// ------------------------------------------------------------- q,k,v GEMMs
// one ds_read_b128 of h feeds 12 FMAs (q,k,v accumulators simultaneously)
__global__ __launch_bounds__(256) void qkv_kernel(const float* __restrict__ h,
        const float* __restrict__ Wq, const float* __restrict__ Wk, const float* __restrict__ Wv,
        const float* __restrict__ bq, const float* __restrict__ bk, const float* __restrict__ bv,
        float* __restrict__ q, float* __restrict__ k, float* __restrict__ v) {
    __shared__ float hs[16 * 128];
    const int tid = threadIdx.x;
    const int row0 = blockIdx.x * 16;
    for (int i = tid; i < 16 * 128; i += 256) hs[i] = h[(size_t)row0 * 128 + i];
    __syncthreads();
    const int c = tid & 127;
    const int g = tid >> 7;   // 0 or 1
    float aq[8], ak[8], av[8];
#pragma unroll
    for (int r = 0; r < 8; ++r) { aq[r] = 0.f; ak[r] = 0.f; av[r] = 0.f; }
    for (int kk = 0; kk < 128; kk += 4) {
        float wq0 = Wq[(kk + 0) * 128 + c], wq1 = Wq[(kk + 1) * 128 + c];
        float wq2 = Wq[(kk + 2) * 128 + c], wq3 = Wq[(kk + 3) * 128 + c];
        float wk0 = Wk[(kk + 0) * 128 + c], wk1 = Wk[(kk + 1) * 128 + c];
        float wk2 = Wk[(kk + 2) * 128 + c], wk3 = Wk[(kk + 3) * 128 + c];
        float wv0 = Wv[(kk + 0) * 128 + c], wv1 = Wv[(kk + 1) * 128 + c];
        float wv2 = Wv[(kk + 2) * 128 + c], wv3 = Wv[(kk + 3) * 128 + c];
#pragma unroll
        for (int r = 0; r < 8; ++r) {
            const float4 hv = *reinterpret_cast<const float4*>(&hs[(g * 8 + r) * 128 + kk]);
            aq[r] += hv.x * wq0 + hv.y * wq1 + hv.z * wq2 + hv.w * wq3;
            ak[r] += hv.x * wk0 + hv.y * wk1 + hv.z * wk2 + hv.w * wk3;
            av[r] += hv.x * wv0 + hv.y * wv1 + hv.z * wv2 + hv.w * wv3;
        }
    }
    const float bqv = bq[c], bkv = bk[c], bvv = bv[c];
#pragma unroll
    for (int r = 0; r < 8; ++r) {
        const size_t o = (size_t)(row0 + g * 8 + r) * 128 + c;
        q[o] = aq[r] + bqv;
        k[o] = ak[r] + bkv;
        v[o] = av[r] + bvv;
    }
}

// --------------------------------------------- per-node fused softmax + agg
// one block (128 threads) per node, phased:
//  A: logits for 16 edges x 8 heads in parallel (private 16-dim dots, no shfl)
//  B: per-head chunk max / exp / denom merge (one shuffle-reduce per chunk)
//  C: weighted v/x gather-accumulate, all iterations independent
__global__ __launch_bounds__(128) void node_kernel(const float* __restrict__ q,
        const float* __restrict__ k, const float* __restrict__ v,
        const float* __restrict__ x, const float* __restrict__ biasS,
        const int* __restrict__ dstS, const int* __restrict__ start,
        float* __restrict__ h_update, float* __restrict__ disp) {
    __shared__ int   dnLds[CH];
    __shared__ float peLds[CH * 8];   // logits, then exp-weights
    __shared__ float qLds[128];
    __shared__ float mLds[8], dLds[8], corrLds[8];
    __shared__ float sd[8][3];

    const int n = blockIdx.x;
    const int t = threadIdx.x;
    const int s0 = start[n], s1 = start[n + 1];

    qLds[t] = q[(size_t)n * 128 + t];
    if (t < 8) { mLds[t] = -INFINITY; dLds[t] = 0.f; }

    const int hhC = t >> 4, dC = t & 15;
    const float xs = (dC < 3) ? x[(size_t)n * 3 + dC] : 0.f;
    float acc = 0.f, accD = 0.f;

    for (int base = s0; base < s1; base += CH) {
        const int en = min(CH, s1 - base);
        __syncthreads();                       // LDS reuse fence
        if (t < en) dnLds[t] = dstS[base + t];
        __syncthreads();
        // ---- phase A: logits ----
        const int eA = t >> 3, hA = t & 7;
        for (int p0 = 0; p0 < en; p0 += 16) {
            const int e = p0 + eA;
            if (e < en) {
                const float* krow = &k[(size_t)dnLds[e] * 128 + hA * 16];
                const float* qrow = &qLds[hA * 16];
                float s = 0.f;
#pragma unroll
                for (int i = 0; i < 16; i += 4) {
                    const float4 kv = *reinterpret_cast<const float4*>(krow + i);
                    const float4 qv = *reinterpret_cast<const float4*>(qrow + i);
                    s += kv.x * qv.x + kv.y * qv.y + kv.z * qv.z + kv.w * qv.w;
                }
                peLds[e * 8 + hA] = s * 0.25f + biasS[(size_t)(base + e) * 8 + hA];
            }
        }
        __syncthreads();
        // ---- phase B: per-head softmax pieces ----
        if (t < 64) {
            const int hB = t >> 3, j = t & 7;
            float cm = -INFINITY;
            for (int e = j; e < en; e += 8) cm = fmaxf(cm, peLds[e * 8 + hB]);
            cm = fmaxf(cm, __shfl_xor(cm, 1));
            cm = fmaxf(cm, __shfl_xor(cm, 2));
            cm = fmaxf(cm, __shfl_xor(cm, 4));
            const float mo = mLds[hB];
            const float nm = fmaxf(mo, cm);
            float sum = 0.f;
            for (int e = j; e < en; e += 8) {
                const float pe = __expf(peLds[e * 8 + hB] - nm);
                peLds[e * 8 + hB] = pe;
                sum += pe;
            }
            sum += __shfl_xor(sum, 1);
            sum += __shfl_xor(sum, 2);
            sum += __shfl_xor(sum, 4);
            if (j == 0) {
                const float corr = __expf(mo - nm);   // 0 on first chunk
                corrLds[hB] = corr;
                dLds[hB] = dLds[hB] * corr + sum;
                mLds[hB] = nm;
            }
        }
        __syncthreads();
        // ---- phase C: independent gather-accumulate ----
        const float corr = corrLds[hhC];
        acc *= corr;
        if (dC < 3) accD *= corr;
#pragma unroll 4
        for (int e = 0; e < en; ++e) {
            const float pe = peLds[e * 8 + hhC];
            const float vv = v[(size_t)dnLds[e] * 128 + t];
            acc += pe * vv;
            if (dC < 3) accD += pe * (x[(size_t)dnLds[e] * 3 + dC] - xs);
        }
    }
    const float w = 1.0f / fmaxf(dLds[hhC], 1e-9f);
    h_update[(size_t)n * 128 + t] = acc * w;
    if (dC < 3) sd[hhC][dC] = accD * w * 0.125f;
    __syncthreads();
    if (t < 3) {
        float s = 0.f;
#pragma unroll
        for (int i = 0; i < 8; ++i) s += sd[i][t];
        disp[(size_t)n * 3 + t] = s;
    }
}

// ------------------------------------- fused output GEMM + gate MLP + coords
__global__ __launch_bounds__(256) void out_kernel(const float* __restrict__ h,
        const float* __restrict__ x, const float* __restrict__ hu,
        const float* __restrict__ Wo, const float* __restrict__ bo,
        const float* __restrict__ Wg1, const float* __restrict__ bg1,
        const float* __restrict__ wg2, const float* __restrict__ bg2,
        const float* __restrict__ disp,
        float* __restrict__ hout, float* __restrict__ xout) {
    __shared__ float bufA[16 * 128];
    __shared__ float bufB[16 * 128];
    const int tid = threadIdx.x;
    const int row0 = blockIdx.x * 16;
    for (int i = tid; i < 16 * 128; i += 256) bufA[i] = hu[(size_t)row0 * 128 + i];
    __syncthreads();
    const int c = tid & 127;
    const int g = tid >> 7;
    float acc[8];
#pragma unroll
    for (int r = 0; r < 8; ++r) acc[r] = 0.f;
    for (int kk = 0; kk < 128; kk += 4) {
        float w0 = Wo[(kk + 0) * 128 + c];
        float w1 = Wo[(kk + 1) * 128 + c];
        float w2 = Wo[(kk + 2) * 128 + c];
        float w3 = Wo[(kk + 3) * 128 + c];
#pragma unroll
        for (int r = 0; r < 8; ++r) {
            const float4 hv = *reinterpret_cast<const float4*>(&bufA[(g * 8 + r) * 128 + kk]);
            acc[r] += hv.x * w0 + hv.y * w1 + hv.z * w2 + hv.w * w3;
        }
    }
    float bov = bo[c];
#pragma unroll
    for (int r = 0; r < 8; ++r) {
        int row = row0 + g * 8 + r;
        float ho = h[(size_t)row * 128 + c] + acc[r] + bov;
        hout[(size_t)row * 128 + c] = ho;
        bufB[(g * 8 + r) * 128 + c] = ho;
    }
    __syncthreads();
    // stage 2: g1 = silu(h_out @ Wg1 + bg1)
#pragma unroll
    for (int r = 0; r < 8; ++r) acc[r] = 0.f;
    for (int kk = 0; kk < 128; kk += 4) {
        float w0 = Wg1[(kk + 0) * 128 + c];
        float w1 = Wg1[(kk + 1) * 128 + c];
        float w2 = Wg1[(kk + 2) * 128 + c];
        float w3 = Wg1[(kk + 3) * 128 + c];
#pragma unroll
        for (int r = 0; r < 8; ++r) {
            const float4 hv = *reinterpret_cast<const float4*>(&bufB[(g * 8 + r) * 128 + kk]);
            acc[r] += hv.x * w0 + hv.y * w1 + hv.z * w2 + hv.w * w3;
        }
    }
    float bg1v = bg1[c];
#pragma unroll
    for (int r = 0; r < 8; ++r) {
        float a = acc[r] + bg1v;
        float s = a / (1.f + __expf(-a));   // silu
        bufA[(g * 8 + r) * 128 + c] = s;
    }
    __syncthreads();
    // gate = tanh(g1 @ wg2 + bg2); x_out = x + gate * disp
    {
        int r = tid >> 4, j = tid & 15;
        float partial = 0.f;
        for (int cc = j; cc < 128; cc += 16) partial += bufA[r * 128 + cc] * wg2[cc];
        partial += __shfl_xor(partial, 1);
        partial += __shfl_xor(partial, 2);
        partial += __shfl_xor(partial, 4);
        partial += __shfl_xor(partial, 8);
        float gate = tanhf(partial + bg2[0]);
        if (j < 3) {
            int row = row0 + r;
            xout[(size_t)row * 3 + j] = x[(size_t)row * 3 + j] + gate * disp[(size_t)row * 3 + j];
        }
    }
}

// ---------------------------------------------------------------- launcher

extern "C" void kernel_launch(void* const* d_in, const int* in_sizes, int n_in,
                              void* d_out, int out_size, void* d_ws, size_t ws_size,
                              hipStream_t stream) {
    const float* h     = (const float*)d_in[0];
    const float* x     = (const float*)d_in[1];
    const int*   src   = (const int*)d_in[2];
    const int*   dst   = (const int*)d_in[3];
    const float* dist  = (const float*)d_in[4];
    const float* bpp   = (const float*)d_in[5];
    const float* msa   = (const float*)d_in[6];
    const float* chem  = (const float*)d_in[7];
    const float* rel   = (const float*)d_in[8];
    const float* chain = (const float*)d_in[9];
    const float* Wq = (const float*)d_in[10];
    const float* Wk = (const float*)d_in[11];
    const float* Wv = (const float*)d_in[12];
    const float* Wo = (const float*)d_in[13];
    const float* bq = (const float*)d_in[14];
    const float* bk = (const float*)d_in[15];
    const float* bv = (const float*)d_in[16];
    const float* bo = (const float*)d_in[17];
    const float* w_dist = (const float*)d_in[18];  const float* b_dist = (const float*)d_in[19];
    const float* w_bpp  = (const float*)d_in[20];  const float* b_bpp  = (const float*)d_in[21];
    const float* w_msa  = (const float*)d_in[22];  const float* b_msa  = (const float*)d_in[23];
    const float* w_chem = (const float*)d_in[24];  const float* b_chem = (const float*)d_in[25];
    const float* w_rel  = (const float*)d_in[26];  const float* b_rel  = (const float*)d_in[27];
    const float* w_chain= (const float*)d_in[28];  const float* b_chain= (const float*)d_in[29];
    const float* Wg1 = (const float*)d_in[30];
    const float* bg1 = (const float*)d_in[31];
    const float* wg2 = (const float*)d_in[32];
    const float* bg2 = (const float*)d_in[33];

    float* fws   = (float*)d_ws;
    float* q     = fws;                           // N*128
    float* k     = q + (size_t)N_NODES * HID;     // N*128
    float* v     = k + (size_t)N_NODES * HID;     // N*128
    float* hu    = v + (size_t)N_NODES * HID;     // N*128
    float* biasS = hu + (size_t)N_NODES * HID;    // E*8
    float* disp  = biasS + (size_t)N_EDGES * 8;   // N*3
    int* dstS    = (int*)(disp + (size_t)N_NODES * 3);  // E
    int* startp  = dstS + N_EDGES;                // N+1
    int* cnt     = startp + (N_NODES + 1);        // N
    int* blockSums = cnt + N_NODES;               // NB_SCAN+1

    float* hout = (float*)d_out;
    float* xout = hout + (size_t)N_NODES * HID;

    hipLaunchKernelGGL(zero_int_kernel, dim3((N_NODES + 255) / 256), dim3(256), 0, stream,
                       cnt, N_NODES);
    hipLaunchKernelGGL(hist_kernel, dim3(N_EDGES / 256), dim3(256), 0, stream, src, cnt);
    hipLaunchKernelGGL(scan1_kernel, dim3(NB_SCAN), dim3(256), 0, stream,
                       cnt, startp, blockSums, N_NODES);
    hipLaunchKernelGGL(scan2_kernel, dim3(1), dim3(128), 0, stream, blockSums, NB_SCAN);
    hipLaunchKernelGGL(scan3_kernel, dim3(NB_SCAN), dim3(256), 0, stream,
                       startp, blockSums, N_NODES, NB_SCAN);
    hipLaunchKernelGGL(zero_int_kernel, dim3((N_NODES + 255) / 256), dim3(256), 0, stream,
                       cnt, N_NODES);
    hipLaunchKernelGGL(scatter_kernel, dim3(N_EDGES / 256), dim3(256), 0, stream,
                       src, dst, dist, bpp, msa, chem, rel, chain,
                       w_dist, b_dist, w_bpp, b_bpp, w_msa, b_msa,
                       w_chem, b_chem, w_rel, b_rel, w_chain, b_chain,
                       startp, cnt, dstS, biasS);
    hipLaunchKernelGGL(qkv_kernel, dim3(N_NODES / 16), dim3(256), 0, stream,
                       h, Wq, Wk, Wv, bq, bk, bv, q, k, v);
    hipLaunchKernelGGL(node_kernel, dim3(N_NODES), dim3(128), 0, stream,
                       q, k, v, x, biasS, dstS, startp, hu, disp);
    hipLaunchKernelGGL(out_kernel, dim3(N_NODES / 16), dim3(256), 0, stream,
                       h, x, hu, Wo, bo, Wg1, bg1, wg2, bg2, disp, hout, xout);
}

// Round 3
// 262.838 us; speedup vs baseline: 1.3737x; 1.0969x over previous
//
#include <hip/hip_runtime.h>
#include <hip/hip_bf16.h>

#define N_NODES 20000
#define N_EDGES 640000
#define HID 128
#define HEADS 8
#define HD 16
#define NB_SCAN ((N_NODES + 255) / 256)   // 79
#define CH 128                            // max edges per softmax chunk

__device__ __forceinline__ float bflo(unsigned u) {
    union { unsigned i; float f; } x; x.i = u << 16; return x.f;
}
__device__ __forceinline__ float bfhi(unsigned u) {
    union { unsigned i; float f; } x; x.i = u & 0xffff0000u; return x.f;
}

// ---------------------------------------------------------------- utilities

__global__ void hist_kernel(const int* __restrict__ src, int* __restrict__ cnt) {
    int e = blockIdx.x * 256 + threadIdx.x;
    if (e < N_EDGES) atomicAdd(&cnt[src[e]], 1);
}

// local block scans (also zeroes cnt for reuse as scatter cursor)
__global__ __launch_bounds__(256) void scan1_kernel(int* __restrict__ cnt,
        int* __restrict__ startp, int* __restrict__ blockSums, int n) {
    __shared__ int sd[256];
    const int tid = threadIdx.x;
    const int i = blockIdx.x * 256 + tid;
    int xv = (i < n) ? cnt[i] : 0;
    sd[tid] = xv;
    __syncthreads();
#pragma unroll
    for (int off = 1; off < 256; off <<= 1) {
        int tv = (tid >= off) ? sd[tid - off] : 0;
        __syncthreads();
        sd[tid] += tv;
        __syncthreads();
    }
    if (i < n) { startp[i] = sd[tid] - xv; cnt[i] = 0; }
    if (tid == 255) blockSums[blockIdx.x] = sd[255];
}

__global__ __launch_bounds__(128) void scan2_kernel(int* __restrict__ blockSums, int nb) {
    __shared__ int sd[128];
    const int tid = threadIdx.x;
    int xv = (tid < nb) ? blockSums[tid] : 0;
    sd[tid] = xv;
    __syncthreads();
#pragma unroll
    for (int off = 1; off < 128; off <<= 1) {
        int tv = (tid >= off) ? sd[tid - off] : 0;
        __syncthreads();
        sd[tid] += tv;
        __syncthreads();
    }
    if (tid < nb) blockSums[tid] = sd[tid] - xv;   // exclusive
    if (tid == 127) blockSums[nb] = sd[127];       // total
}

// scatter edges into src-sorted order; pre-bake the 6 edge-bias heads
__global__ void scatter_kernel(const int* __restrict__ src, const int* __restrict__ dst,
                               const float* __restrict__ dist, const float* __restrict__ bpp,
                               const float* __restrict__ msa, const float* __restrict__ chem,
                               const float* __restrict__ rel, const float* __restrict__ chain,
                               const float* __restrict__ w_dist, const float* __restrict__ b_dist,
                               const float* __restrict__ w_bpp, const float* __restrict__ b_bpp,
                               const float* __restrict__ w_msa, const float* __restrict__ b_msa,
                               const float* __restrict__ w_chem, const float* __restrict__ b_chem,
                               const float* __restrict__ w_rel, const float* __restrict__ b_rel,
                               const float* __restrict__ w_chain, const float* __restrict__ b_chain,
                               const int* __restrict__ startp, const int* __restrict__ blockSums,
                               int* __restrict__ cnt,
                               int* __restrict__ dstS, float* __restrict__ biasS) {
    int e = blockIdx.x * 256 + threadIdx.x;
    if (e >= N_EDGES) return;
    int s = src[e];
    int pos = startp[s] + blockSums[s >> 8] + atomicAdd(&cnt[s], 1);
    dstS[pos] = dst[e];
    float d2 = dist[e] * dist[e];
    float f_bpp = bpp[e], f_msa = msa[e], f_chem = chem[e], f_rel = rel[e], f_chain = chain[e];
    float out[8];
#pragma unroll
    for (int h = 0; h < 8; ++h) {
        float b = -(d2 * w_dist[h] + b_dist[h])
                + (f_bpp * w_bpp[h] + b_bpp[h])
                + (f_msa * w_msa[h] + b_msa[h])
                + (f_chem * w_chem[h] + b_chem[h])
                + (f_rel * w_rel[h] + b_rel[h])
                + (f_chain * w_chain[h] + b_chain[h]);
        out[h] = b;
    }
    float4* bp = reinterpret_cast<float4*>(&biasS[(size_t)pos * 8]);
    bp[0] = make_float4(out[0], out[1], out[2], out[3]);
    bp[1] = make_float4(out[4], out[5], out[6], out[7]);
}

// ------------------------------------------------------------- q,k,v GEMMs
// q stays fp32 (read once per node); k,v written as bf16 (gathered per edge)
__global__ __launch_bounds__(256) void qkv_kernel(const float* __restrict__ h,
        const float* __restrict__ Wq, const float* __restrict__ Wk, const float* __restrict__ Wv,
        const float* __restrict__ bq, const float* __restrict__ bk, const float* __restrict__ bv,
        float* __restrict__ q, __hip_bfloat16* __restrict__ k_bf,
        __hip_bfloat16* __restrict__ v_bf) {
    __shared__ float hs[16 * 128];
    const int tid = threadIdx.x;
    const int row0 = blockIdx.x * 16;
    for (int i = tid; i < 16 * 128; i += 256) hs[i] = h[(size_t)row0 * 128 + i];
    __syncthreads();
    const int c = tid & 127;
    const int g = tid >> 7;   // 0 or 1
    float aq[8], ak[8], av[8];
#pragma unroll
    for (int r = 0; r < 8; ++r) { aq[r] = 0.f; ak[r] = 0.f; av[r] = 0.f; }
    for (int kk = 0; kk < 128; kk += 4) {
        float wq0 = Wq[(kk + 0) * 128 + c], wq1 = Wq[(kk + 1) * 128 + c];
        float wq2 = Wq[(kk + 2) * 128 + c], wq3 = Wq[(kk + 3) * 128 + c];
        float wk0 = Wk[(kk + 0) * 128 + c], wk1 = Wk[(kk + 1) * 128 + c];
        float wk2 = Wk[(kk + 2) * 128 + c], wk3 = Wk[(kk + 3) * 128 + c];
        float wv0 = Wv[(kk + 0) * 128 + c], wv1 = Wv[(kk + 1) * 128 + c];
        float wv2 = Wv[(kk + 2) * 128 + c], wv3 = Wv[(kk + 3) * 128 + c];
#pragma unroll
        for (int r = 0; r < 8; ++r) {
            const float4 hv = *reinterpret_cast<const float4*>(&hs[(g * 8 + r) * 128 + kk]);
            aq[r] += hv.x * wq0 + hv.y * wq1 + hv.z * wq2 + hv.w * wq3;
            ak[r] += hv.x * wk0 + hv.y * wk1 + hv.z * wk2 + hv.w * wk3;
            av[r] += hv.x * wv0 + hv.y * wv1 + hv.z * wv2 + hv.w * wv3;
        }
    }
    const float bqv = bq[c], bkv = bk[c], bvv = bv[c];
#pragma unroll
    for (int r = 0; r < 8; ++r) {
        const size_t o = (size_t)(row0 + g * 8 + r) * 128 + c;
        q[o] = aq[r] + bqv;
        k_bf[o] = __float2bfloat16(ak[r] + bkv);
        v_bf[o] = __float2bfloat16(av[r] + bvv);
    }
}

// --------------------------------------------- per-node fused softmax + agg
__global__ __launch_bounds__(128) void node_kernel(const float* __restrict__ q,
        const __hip_bfloat16* __restrict__ k_bf, const __hip_bfloat16* __restrict__ v_bf,
        const float* __restrict__ x, const float* __restrict__ biasS,
        const int* __restrict__ dstS, const int* __restrict__ startp,
        const int* __restrict__ blockSums,
        float* __restrict__ h_update, float* __restrict__ disp) {
    __shared__ int   dnLds[CH];
    __shared__ float peLds[CH * 8];   // logits, then exp-weights
    __shared__ float qLds[128];
    __shared__ float mLds[8], dLds[8], corrLds[8];
    __shared__ float sd[8][3];

    const int n = blockIdx.x;
    const int t = threadIdx.x;
    const int s0 = startp[n] + blockSums[n >> 8];
    const int s1 = (n + 1 < N_NODES) ? (startp[n + 1] + blockSums[(n + 1) >> 8]) : N_EDGES;

    qLds[t] = q[(size_t)n * 128 + t];
    if (t < 8) { mLds[t] = -INFINITY; dLds[t] = 0.f; }

    const int hhC = t >> 4, dC = t & 15;
    const float xs = (dC < 3) ? x[(size_t)n * 3 + dC] : 0.f;
    float acc = 0.f, accD = 0.f;

    for (int base = s0; base < s1; base += CH) {
        const int en = min(CH, s1 - base);
        __syncthreads();                       // LDS reuse fence
        if (t < en) dnLds[t] = dstS[base + t];
        __syncthreads();
        // ---- phase A: logits (bf16 k rows, 2x uint4 per lane) ----
        const int eA = t >> 3, hA = t & 7;
        for (int p0 = 0; p0 < en; p0 += 16) {
            const int e = p0 + eA;
            if (e < en) {
                const ushort* krow = reinterpret_cast<const ushort*>(k_bf)
                                     + (size_t)dnLds[e] * 128 + hA * 16;
                const uint4 ka = *reinterpret_cast<const uint4*>(krow);
                const uint4 kb = *reinterpret_cast<const uint4*>(krow + 8);
                const float* qrow = &qLds[hA * 16];
                float s = 0.f;
                const unsigned* kau = reinterpret_cast<const unsigned*>(&ka);
                const unsigned* kbu = reinterpret_cast<const unsigned*>(&kb);
#pragma unroll
                for (int i = 0; i < 4; ++i) {
                    s += bflo(kau[i]) * qrow[2 * i]     + bfhi(kau[i]) * qrow[2 * i + 1];
                    s += bflo(kbu[i]) * qrow[8 + 2 * i] + bfhi(kbu[i]) * qrow[8 + 2 * i + 1];
                }
                peLds[e * 8 + hA] = s * 0.25f + biasS[(size_t)(base + e) * 8 + hA];
            }
        }
        __syncthreads();
        // ---- phase B: per-head softmax pieces ----
        if (t < 64) {
            const int hB = t >> 3, j = t & 7;
            float cm = -INFINITY;
            for (int e = j; e < en; e += 8) cm = fmaxf(cm, peLds[e * 8 + hB]);
            cm = fmaxf(cm, __shfl_xor(cm, 1));
            cm = fmaxf(cm, __shfl_xor(cm, 2));
            cm = fmaxf(cm, __shfl_xor(cm, 4));
            const float mo = mLds[hB];
            const float nm = fmaxf(mo, cm);
            float sum = 0.f;
            for (int e = j; e < en; e += 8) {
                const float pe = __expf(peLds[e * 8 + hB] - nm);
                peLds[e * 8 + hB] = pe;
                sum += pe;
            }
            sum += __shfl_xor(sum, 1);
            sum += __shfl_xor(sum, 2);
            sum += __shfl_xor(sum, 4);
            if (j == 0) {
                const float corr = __expf(mo - nm);   // 0 on first chunk
                corrLds[hB] = corr;
                dLds[hB] = dLds[hB] * corr + sum;
                mLds[hB] = nm;
            }
        }
        __syncthreads();
        // ---- phase C: independent gather-accumulate (bf16 v rows) ----
        const float corr = corrLds[hhC];
        acc *= corr;
        if (dC < 3) accD *= corr;
#pragma unroll 4
        for (int e = 0; e < en; ++e) {
            const float pe = peLds[e * 8 + hhC];
            const float vv = __bfloat162float(v_bf[(size_t)dnLds[e] * 128 + t]);
            acc += pe * vv;
            if (dC < 3) accD += pe * (x[(size_t)dnLds[e] * 3 + dC] - xs);
        }
    }
    const float w = 1.0f / fmaxf(dLds[hhC], 1e-9f);
    h_update[(size_t)n * 128 + t] = acc * w;
    if (dC < 3) sd[hhC][dC] = accD * w * 0.125f;
    __syncthreads();
    if (t < 3) {
        float s = 0.f;
#pragma unroll
        for (int i = 0; i < 8; ++i) s += sd[i][t];
        disp[(size_t)n * 3 + t] = s;
    }
}

// ------------------------------------- fused output GEMM + gate MLP + coords
__global__ __launch_bounds__(256) void out_kernel(const float* __restrict__ h,
        const float* __restrict__ x, const float* __restrict__ hu,
        const float* __restrict__ Wo, const float* __restrict__ bo,
        const float* __restrict__ Wg1, const float* __restrict__ bg1,
        const float* __restrict__ wg2, const float* __restrict__ bg2,
        const float* __restrict__ disp,
        float* __restrict__ hout, float* __restrict__ xout) {
    __shared__ float bufA[16 * 128];
    __shared__ float bufB[16 * 128];
    const int tid = threadIdx.x;
    const int row0 = blockIdx.x * 16;
    for (int i = tid; i < 16 * 128; i += 256) bufA[i] = hu[(size_t)row0 * 128 + i];
    __syncthreads();
    const int c = tid & 127;
    const int g = tid >> 7;
    float acc[8];
#pragma unroll
    for (int r = 0; r < 8; ++r) acc[r] = 0.f;
    for (int kk = 0; kk < 128; kk += 4) {
        float w0 = Wo[(kk + 0) * 128 + c];
        float w1 = Wo[(kk + 1) * 128 + c];
        float w2 = Wo[(kk + 2) * 128 + c];
        float w3 = Wo[(kk + 3) * 128 + c];
#pragma unroll
        for (int r = 0; r < 8; ++r) {
            const float4 hv = *reinterpret_cast<const float4*>(&bufA[(g * 8 + r) * 128 + kk]);
            acc[r] += hv.x * w0 + hv.y * w1 + hv.z * w2 + hv.w * w3;
        }
    }
    float bov = bo[c];
#pragma unroll
    for (int r = 0; r < 8; ++r) {
        int row = row0 + g * 8 + r;
        float ho = h[(size_t)row * 128 + c] + acc[r] + bov;
        hout[(size_t)row * 128 + c] = ho;
        bufB[(g * 8 + r) * 128 + c] = ho;
    }
    __syncthreads();
    // stage 2: g1 = silu(h_out @ Wg1 + bg1)
#pragma unroll
    for (int r = 0; r < 8; ++r) acc[r] = 0.f;
    for (int kk = 0; kk < 128; kk += 4) {
        float w0 = Wg1[(kk + 0) * 128 + c];
        float w1 = Wg1[(kk + 1) * 128 + c];
        float w2 = Wg1[(kk + 2) * 128 + c];
        float w3 = Wg1[(kk + 3) * 128 + c];
#pragma unroll
        for (int r = 0; r < 8; ++r) {
            const float4 hv = *reinterpret_cast<const float4*>(&bufB[(g * 8 + r) * 128 + kk]);
            acc[r] += hv.x * w0 + hv.y * w1 + hv.z * w2 + hv.w * w3;
        }
    }
    float bg1v = bg1[c];
#pragma unroll
    for (int r = 0; r < 8; ++r) {
        float a = acc[r] + bg1v;
        float s = a / (1.f + __expf(-a));   // silu
        bufA[(g * 8 + r) * 128 + c] = s;
    }
    __syncthreads();
    // gate = tanh(g1 @ wg2 + bg2); x_out = x + gate * disp
    {
        int r = tid >> 4, j = tid & 15;
        float partial = 0.f;
        for (int cc = j; cc < 128; cc += 16) partial += bufA[r * 128 + cc] * wg2[cc];
        partial += __shfl_xor(partial, 1);
        partial += __shfl_xor(partial, 2);
        partial += __shfl_xor(partial, 4);
        partial += __shfl_xor(partial, 8);
        float gate = tanhf(partial + bg2[0]);
        if (j < 3) {
            int row = row0 + r;
            xout[(size_t)row * 3 + j] = x[(size_t)row * 3 + j] + gate * disp[(size_t)row * 3 + j];
        }
    }
}

// ---------------------------------------------------------------- launcher

extern "C" void kernel_launch(void* const* d_in, const int* in_sizes, int n_in,
                              void* d_out, int out_size, void* d_ws, size_t ws_size,
                              hipStream_t stream) {
    const float* h     = (const float*)d_in[0];
    const float* x     = (const float*)d_in[1];
    const int*   src   = (const int*)d_in[2];
    const int*   dst   = (const int*)d_in[3];
    const float* dist  = (const float*)d_in[4];
    const float* bpp   = (const float*)d_in[5];
    const float* msa   = (const float*)d_in[6];
    const float* chem  = (const float*)d_in[7];
    const float* rel   = (const float*)d_in[8];
    const float* chain = (const float*)d_in[9];
    const float* Wq = (const float*)d_in[10];
    const float* Wk = (const float*)d_in[11];
    const float* Wv = (const float*)d_in[12];
    const float* Wo = (const float*)d_in[13];
    const float* bq = (const float*)d_in[14];
    const float* bk = (const float*)d_in[15];
    const float* bv = (const float*)d_in[16];
    const float* bo = (const float*)d_in[17];
    const float* w_dist = (const float*)d_in[18];  const float* b_dist = (const float*)d_in[19];
    const float* w_bpp  = (const float*)d_in[20];  const float* b_bpp  = (const float*)d_in[21];
    const float* w_msa  = (const float*)d_in[22];  const float* b_msa  = (const float*)d_in[23];
    const float* w_chem = (const float*)d_in[24];  const float* b_chem = (const float*)d_in[25];
    const float* w_rel  = (const float*)d_in[26];  const float* b_rel  = (const float*)d_in[27];
    const float* w_chain= (const float*)d_in[28];  const float* b_chain= (const float*)d_in[29];
    const float* Wg1 = (const float*)d_in[30];
    const float* bg1 = (const float*)d_in[31];
    const float* wg2 = (const float*)d_in[32];
    const float* bg2 = (const float*)d_in[33];

    float* fws   = (float*)d_ws;
    float* q     = fws;                           // N*128 f32
    float* hu    = q + (size_t)N_NODES * HID;     // N*128 f32
    float* biasS = hu + (size_t)N_NODES * HID;    // E*8 f32
    float* disp  = biasS + (size_t)N_EDGES * 8;   // N*3 f32
    __hip_bfloat16* k_bf = (__hip_bfloat16*)(disp + (size_t)N_NODES * 3);  // N*128 bf16
    __hip_bfloat16* v_bf = k_bf + (size_t)N_NODES * HID;                   // N*128 bf16
    int* dstS    = (int*)(v_bf + (size_t)N_NODES * HID);  // E
    int* startp  = dstS + N_EDGES;                // N (local scans)
    int* cnt     = startp + N_NODES;              // N
    int* blockSums = cnt + N_NODES;               // NB_SCAN+1

    float* hout = (float*)d_out;
    float* xout = hout + (size_t)N_NODES * HID;

    hipMemsetAsync(cnt, 0, (size_t)N_NODES * sizeof(int), stream);
    hipLaunchKernelGGL(hist_kernel, dim3(N_EDGES / 256), dim3(256), 0, stream, src, cnt);
    hipLaunchKernelGGL(scan1_kernel, dim3(NB_SCAN), dim3(256), 0, stream,
                       cnt, startp, blockSums, N_NODES);
    hipLaunchKernelGGL(scan2_kernel, dim3(1), dim3(128), 0, stream, blockSums, NB_SCAN);
    hipLaunchKernelGGL(scatter_kernel, dim3(N_EDGES / 256), dim3(256), 0, stream,
                       src, dst, dist, bpp, msa, chem, rel, chain,
                       w_dist, b_dist, w_bpp, b_bpp, w_msa, b_msa,
                       w_chem, b_chem, w_rel, b_rel, w_chain, b_chain,
                       startp, blockSums, cnt, dstS, biasS);
    hipLaunchKernelGGL(qkv_kernel, dim3(N_NODES / 16), dim3(256), 0, stream,
                       h, Wq, Wk, Wv, bq, bk, bv, q, k_bf, v_bf);
    hipLaunchKernelGGL(node_kernel, dim3(N_NODES), dim3(128), 0, stream,
                       q, k_bf, v_bf, x, biasS, dstS, startp, blockSums, hu, disp);
    hipLaunchKernelGGL(out_kernel, dim3(N_NODES / 16), dim3(256), 0, stream,
                       h, x, hu, Wo, bo, Wg1, bg1, wg2, bg2, disp, hout, xout);
}

// Round 4
// 224.373 us; speedup vs baseline: 1.6092x; 1.1714x over previous
//
#include <hip/hip_runtime.h>
#include <hip/hip_bf16.h>

#define N_NODES 20000
#define N_EDGES 640000
#define HID 128
#define HEADS 8
#define HD 16
#define NB_SCAN ((N_NODES + 255) / 256)   // 79
#define CH 160                            // edges per chunk (covers 4-node union ~99.8%)

__device__ __forceinline__ float bflo(unsigned u) {
    union { unsigned i; float f; } x; x.i = u << 16; return x.f;
}
__device__ __forceinline__ float bfhi(unsigned u) {
    union { unsigned i; float f; } x; x.i = u & 0xffff0000u; return x.f;
}
__device__ __forceinline__ float bfu(ushort u) {
    union { unsigned i; float f; } x; x.i = ((unsigned)u) << 16; return x.f;
}

// ---------------------------------------------------------------- utilities

__global__ void hist_kernel(const int* __restrict__ src, int* __restrict__ cnt) {
    int e = blockIdx.x * 256 + threadIdx.x;
    if (e < N_EDGES) atomicAdd(&cnt[src[e]], 1);
}

// local block scans (also zeroes cnt for reuse as scatter cursor)
__global__ __launch_bounds__(256) void scan1_kernel(int* __restrict__ cnt,
        int* __restrict__ startp, int* __restrict__ blockSums, int n) {
    __shared__ int sd[256];
    const int tid = threadIdx.x;
    const int i = blockIdx.x * 256 + tid;
    int xv = (i < n) ? cnt[i] : 0;
    sd[tid] = xv;
    __syncthreads();
#pragma unroll
    for (int off = 1; off < 256; off <<= 1) {
        int tv = (tid >= off) ? sd[tid - off] : 0;
        __syncthreads();
        sd[tid] += tv;
        __syncthreads();
    }
    if (i < n) { startp[i] = sd[tid] - xv; cnt[i] = 0; }
    if (tid == 255) blockSums[blockIdx.x] = sd[255];
}

__global__ __launch_bounds__(128) void scan2_kernel(int* __restrict__ blockSums, int nb) {
    __shared__ int sd[128];
    const int tid = threadIdx.x;
    int xv = (tid < nb) ? blockSums[tid] : 0;
    sd[tid] = xv;
    __syncthreads();
#pragma unroll
    for (int off = 1; off < 128; off <<= 1) {
        int tv = (tid >= off) ? sd[tid - off] : 0;
        __syncthreads();
        sd[tid] += tv;
        __syncthreads();
    }
    if (tid < nb) blockSums[tid] = sd[tid] - xv;   // exclusive
    if (tid == 127) blockSums[nb] = sd[127];       // total
}

// scatter edges into src-sorted order; pre-bake the 6 edge-bias heads
__global__ void scatter_kernel(const int* __restrict__ src, const int* __restrict__ dst,
                               const float* __restrict__ dist, const float* __restrict__ bpp,
                               const float* __restrict__ msa, const float* __restrict__ chem,
                               const float* __restrict__ rel, const float* __restrict__ chain,
                               const float* __restrict__ w_dist, const float* __restrict__ b_dist,
                               const float* __restrict__ w_bpp, const float* __restrict__ b_bpp,
                               const float* __restrict__ w_msa, const float* __restrict__ b_msa,
                               const float* __restrict__ w_chem, const float* __restrict__ b_chem,
                               const float* __restrict__ w_rel, const float* __restrict__ b_rel,
                               const float* __restrict__ w_chain, const float* __restrict__ b_chain,
                               const int* __restrict__ startp, const int* __restrict__ blockSums,
                               int* __restrict__ cnt,
                               int* __restrict__ dstS, float* __restrict__ biasS) {
    int e = blockIdx.x * 256 + threadIdx.x;
    if (e >= N_EDGES) return;
    int s = src[e];
    int pos = startp[s] + blockSums[s >> 8] + atomicAdd(&cnt[s], 1);
    dstS[pos] = dst[e];
    float d2 = dist[e] * dist[e];
    float f_bpp = bpp[e], f_msa = msa[e], f_chem = chem[e], f_rel = rel[e], f_chain = chain[e];
    float out[8];
#pragma unroll
    for (int h = 0; h < 8; ++h) {
        float b = -(d2 * w_dist[h] + b_dist[h])
                + (f_bpp * w_bpp[h] + b_bpp[h])
                + (f_msa * w_msa[h] + b_msa[h])
                + (f_chem * w_chem[h] + b_chem[h])
                + (f_rel * w_rel[h] + b_rel[h])
                + (f_chain * w_chain[h] + b_chain[h]);
        out[h] = b;
    }
    float4* bp = reinterpret_cast<float4*>(&biasS[(size_t)pos * 8]);
    bp[0] = make_float4(out[0], out[1], out[2], out[3]);
    bp[1] = make_float4(out[4], out[5], out[6], out[7]);
}

// ------------------------------------------------------------- q,k,v GEMMs
// 32-row tiles: 16 rows/thread -> 16:1 FMA:weight-load; weights L2-hot
__global__ __launch_bounds__(256) void qkv_kernel(const float* __restrict__ h,
        const float* __restrict__ Wq, const float* __restrict__ Wk, const float* __restrict__ Wv,
        const float* __restrict__ bq, const float* __restrict__ bk, const float* __restrict__ bv,
        float* __restrict__ q, __hip_bfloat16* __restrict__ k_bf,
        __hip_bfloat16* __restrict__ v_bf) {
    __shared__ float hs[32 * 128];
    const int t = threadIdx.x;
    const int row0 = blockIdx.x * 32;
    for (int i4 = t; i4 < 1024; i4 += 256)
        reinterpret_cast<float4*>(hs)[i4] =
            reinterpret_cast<const float4*>(h + (size_t)row0 * 128)[i4];
    __syncthreads();
    const int c = t & 127;
    const int g = t >> 7;   // rows g*16 .. g*16+15
    float aq[16], ak[16], av[16];
#pragma unroll
    for (int r = 0; r < 16; ++r) { aq[r] = 0.f; ak[r] = 0.f; av[r] = 0.f; }
    for (int kk = 0; kk < 128; kk += 4) {
        float wq0 = Wq[(kk + 0) * 128 + c], wq1 = Wq[(kk + 1) * 128 + c];
        float wq2 = Wq[(kk + 2) * 128 + c], wq3 = Wq[(kk + 3) * 128 + c];
        float wk0 = Wk[(kk + 0) * 128 + c], wk1 = Wk[(kk + 1) * 128 + c];
        float wk2 = Wk[(kk + 2) * 128 + c], wk3 = Wk[(kk + 3) * 128 + c];
        float wv0 = Wv[(kk + 0) * 128 + c], wv1 = Wv[(kk + 1) * 128 + c];
        float wv2 = Wv[(kk + 2) * 128 + c], wv3 = Wv[(kk + 3) * 128 + c];
#pragma unroll
        for (int r = 0; r < 16; ++r) {
            const float4 hv = *reinterpret_cast<const float4*>(&hs[(g * 16 + r) * 128 + kk]);
            aq[r] += hv.x * wq0 + hv.y * wq1 + hv.z * wq2 + hv.w * wq3;
            ak[r] += hv.x * wk0 + hv.y * wk1 + hv.z * wk2 + hv.w * wk3;
            av[r] += hv.x * wv0 + hv.y * wv1 + hv.z * wv2 + hv.w * wv3;
        }
    }
    const float bqv = bq[c], bkv = bk[c], bvv = bv[c];
#pragma unroll
    for (int r = 0; r < 16; ++r) {
        const size_t o = (size_t)(row0 + g * 16 + r) * 128 + c;
        q[o] = aq[r] + bqv;
        k_bf[o] = __float2bfloat16(ak[r] + bkv);
        v_bf[o] = __float2bfloat16(av[r] + bvv);
    }
}

// --------------------------------------------- per-node fused softmax + agg
// 4 nodes / 256-thread block, single-pass softmax (no max: logits bounded),
// phases: stage dn/x -> A: exp-logits (e,h pairs) -> C: per-node gather-acc.
__global__ __launch_bounds__(256) void node_kernel(const float* __restrict__ q,
        const ushort* __restrict__ k_bf, const ushort* __restrict__ v_bf,
        const float* __restrict__ x, const float* __restrict__ biasS,
        const int* __restrict__ dstS, const int* __restrict__ startp,
        const int* __restrict__ blockSums,
        float* __restrict__ h_update, float* __restrict__ disp) {
    __shared__ float qLds[4 * 128];
    __shared__ float xsLds[12];
    __shared__ int   sLds[5];
    __shared__ int   dnLds[CH];
    __shared__ float xLds[CH * 3 + 4];
    __shared__ float peLds[CH * 8];
    __shared__ float redLds[4 * 256];
    __shared__ float denLds[256];
    __shared__ float adxLds[256];
    __shared__ float dpLds[32];

    const int t = threadIdx.x;
    const int n0 = blockIdx.x * 4;

    for (int i = t; i < 4 * 128; i += 256) qLds[i] = q[(size_t)n0 * 128 + i];
    if (t < 12) xsLds[t] = x[(size_t)n0 * 3 + t];
    if (t < 5) {
        int idx = n0 + t;
        sLds[t] = (idx < N_NODES) ? (startp[idx] + blockSums[idx >> 8]) : N_EDGES;
    }
    __syncthreads();

    const int S0 = sLds[0], S4 = sLds[4];
    const int s1r = sLds[1], s2r = sLds[2], s3r = sLds[3];

    const int eg = t >> 5;          // 0..7 edge-group
    const int dq = t & 31;          // dim-quad: dims 4dq..4dq+3
    const int hh = dq >> 2;         // head
    const int jj = dq & 3;
    const int j3 = (jj < 3) ? jj : 0;

    float acc0[4] = {0,0,0,0}, acc1[4] = {0,0,0,0};
    float acc2[4] = {0,0,0,0}, acc3[4] = {0,0,0,0};
    float den0 = 0, den1 = 0, den2 = 0, den3 = 0;
    float adx0 = 0, adx1 = 0, adx2 = 0, adx3 = 0;

    for (int base = S0; base < S4; base += CH) {
        const int en = min(CH, S4 - base);
        __syncthreads();                       // protect LDS from prev phase C
        if (t < en) {
            int dn = dstS[base + t];
            dnLds[t] = dn;
            xLds[t * 3 + 0] = x[(size_t)dn * 3 + 0];
            xLds[t * 3 + 1] = x[(size_t)dn * 3 + 1];
            xLds[t * 3 + 2] = x[(size_t)dn * 3 + 2];
        }
        __syncthreads();
        // ---- phase A: exp-logits for (edge, head) pairs ----
        const int np = en * 8;
        for (int p = t; p < np; p += 256) {
            const int e = p >> 3, ha = p & 7;
            const int ge = base + e;
            const int m = (ge >= s1r) + (ge >= s2r) + (ge >= s3r);
            const ushort* krow = k_bf + (size_t)dnLds[e] * 128 + ha * 16;
            const uint4 ka = *reinterpret_cast<const uint4*>(krow);
            const uint4 kb = *reinterpret_cast<const uint4*>(krow + 8);
            const float* qrow = &qLds[m * 128 + ha * 16];
            const unsigned* kau = reinterpret_cast<const unsigned*>(&ka);
            const unsigned* kbu = reinterpret_cast<const unsigned*>(&kb);
            float s = 0.f;
#pragma unroll
            for (int i = 0; i < 4; ++i) {
                s += bflo(kau[i]) * qrow[2 * i]     + bfhi(kau[i]) * qrow[2 * i + 1];
                s += bflo(kbu[i]) * qrow[8 + 2 * i] + bfhi(kbu[i]) * qrow[8 + 2 * i + 1];
            }
            peLds[p] = __expf(fmaf(s, 0.25f, biasS[(size_t)ge * 8 + ha]));
        }
        __syncthreads();
        // ---- phase C: per-node gather-accumulate (compile-time node idx) ----
#define NODE_C(M, ACC, DEN, ADX) { \
            const int lo = max(sLds[M] - base, 0); \
            const int hi = min(sLds[M + 1] - base, en); \
            const float xsv = xsLds[M * 3 + j3]; \
            for (int e = lo + eg; e < hi; e += 8) { \
                const float pe = peLds[e * 8 + hh]; \
                const ushort4 vv = *reinterpret_cast<const ushort4*>( \
                    v_bf + (size_t)dnLds[e] * 128 + dq * 4); \
                ACC[0] = fmaf(pe, bfu(vv.x), ACC[0]); \
                ACC[1] = fmaf(pe, bfu(vv.y), ACC[1]); \
                ACC[2] = fmaf(pe, bfu(vv.z), ACC[2]); \
                ACC[3] = fmaf(pe, bfu(vv.w), ACC[3]); \
                DEN += pe; \
                ADX = fmaf(pe, xLds[e * 3 + j3] - xsv, ADX); \
            } }
        NODE_C(0, acc0, den0, adx0)
        NODE_C(1, acc1, den1, adx1)
        NODE_C(2, acc2, den2, adx2)
        NODE_C(3, acc3, den3, adx3)
#undef NODE_C
    }

    // ---- final reduce over the 8 edge-groups, one node at a time ----
#define REDUCE_M(M, ACC, DEN, ADX) { \
        redLds[0 * 256 + t] = ACC[0]; redLds[1 * 256 + t] = ACC[1]; \
        redLds[2 * 256 + t] = ACC[2]; redLds[3 * 256 + t] = ACC[3]; \
        denLds[t] = DEN; adxLds[t] = ADX; \
        __syncthreads(); \
        if (t < 128) { \
            const int dqr = t >> 2, jr = t & 3, hr = t >> 4; \
            float s = 0.f, dsum = 0.f; \
            _Pragma("unroll") \
            for (int gg = 0; gg < 8; ++gg) { \
                s += redLds[jr * 256 + gg * 32 + dqr]; \
                dsum += denLds[gg * 32 + hr * 4]; \
            } \
            h_update[(size_t)(n0 + M) * 128 + t] = s / fmaxf(dsum, 1e-9f); \
        } \
        if (t < 32 && jj < 3) { \
            float s = 0.f, dsum = 0.f; \
            _Pragma("unroll") \
            for (int gg = 0; gg < 8; ++gg) { \
                s += adxLds[gg * 32 + hh * 4 + jj]; \
                dsum += denLds[gg * 32 + hh * 4]; \
            } \
            dpLds[hh * 4 + jj] = s / fmaxf(dsum, 1e-9f); \
        } \
        __syncthreads(); \
        if (t < 3) { \
            float s = 0.f; \
            _Pragma("unroll") \
            for (int hq = 0; hq < 8; ++hq) s += dpLds[hq * 4 + t]; \
            disp[(size_t)(n0 + M) * 3 + t] = s * 0.125f; \
        } }
    REDUCE_M(0, acc0, den0, adx0)
    __syncthreads();
    REDUCE_M(1, acc1, den1, adx1)
    __syncthreads();
    REDUCE_M(2, acc2, den2, adx2)
    __syncthreads();
    REDUCE_M(3, acc3, den3, adx3)
#undef REDUCE_M
}

// ------------------------------------- fused output GEMM + gate MLP + coords
// 32-row tiles, 2 cols/thread
__global__ __launch_bounds__(256) void out_kernel(const float* __restrict__ h,
        const float* __restrict__ x, const float* __restrict__ hu,
        const float* __restrict__ Wo, const float* __restrict__ bo,
        const float* __restrict__ Wg1, const float* __restrict__ bg1,
        const float* __restrict__ wg2, const float* __restrict__ bg2,
        const float* __restrict__ disp,
        float* __restrict__ hout, float* __restrict__ xout) {
    __shared__ float bufA[32 * 128];
    __shared__ float bufB[32 * 128];
    const int t = threadIdx.x;
    const int row0 = blockIdx.x * 32;
    for (int i4 = t; i4 < 1024; i4 += 256)
        reinterpret_cast<float4*>(bufA)[i4] =
            reinterpret_cast<const float4*>(hu + (size_t)row0 * 128)[i4];
    __syncthreads();
    const int c2 = (t & 63) * 2;
    const int g = t >> 6;              // rows g*8 .. g*8+7
    float a0[8], a1[8];
#pragma unroll
    for (int r = 0; r < 8; ++r) { a0[r] = 0.f; a1[r] = 0.f; }
    for (int kk = 0; kk < 128; kk += 4) {
        float w00 = Wo[(kk + 0) * 128 + c2], w01 = Wo[(kk + 0) * 128 + c2 + 1];
        float w10 = Wo[(kk + 1) * 128 + c2], w11 = Wo[(kk + 1) * 128 + c2 + 1];
        float w20 = Wo[(kk + 2) * 128 + c2], w21 = Wo[(kk + 2) * 128 + c2 + 1];
        float w30 = Wo[(kk + 3) * 128 + c2], w31 = Wo[(kk + 3) * 128 + c2 + 1];
#pragma unroll
        for (int r = 0; r < 8; ++r) {
            const float4 hv = *reinterpret_cast<const float4*>(&bufA[(g * 8 + r) * 128 + kk]);
            a0[r] += hv.x * w00 + hv.y * w10 + hv.z * w20 + hv.w * w30;
            a1[r] += hv.x * w01 + hv.y * w11 + hv.z * w21 + hv.w * w31;
        }
    }
    const float bo0 = bo[c2], bo1 = bo[c2 + 1];
#pragma unroll
    for (int r = 0; r < 8; ++r) {
        const int row = row0 + g * 8 + r;
        float h0 = h[(size_t)row * 128 + c2]     + a0[r] + bo0;
        float h1 = h[(size_t)row * 128 + c2 + 1] + a1[r] + bo1;
        *reinterpret_cast<float2*>(&hout[(size_t)row * 128 + c2]) = make_float2(h0, h1);
        bufB[(g * 8 + r) * 128 + c2] = h0;
        bufB[(g * 8 + r) * 128 + c2 + 1] = h1;
    }
    __syncthreads();
    // stage 2: silu(h_out @ Wg1 + bg1) -> bufA
#pragma unroll
    for (int r = 0; r < 8; ++r) { a0[r] = 0.f; a1[r] = 0.f; }
    for (int kk = 0; kk < 128; kk += 4) {
        float w00 = Wg1[(kk + 0) * 128 + c2], w01 = Wg1[(kk + 0) * 128 + c2 + 1];
        float w10 = Wg1[(kk + 1) * 128 + c2], w11 = Wg1[(kk + 1) * 128 + c2 + 1];
        float w20 = Wg1[(kk + 2) * 128 + c2], w21 = Wg1[(kk + 2) * 128 + c2 + 1];
        float w30 = Wg1[(kk + 3) * 128 + c2], w31 = Wg1[(kk + 3) * 128 + c2 + 1];
#pragma unroll
        for (int r = 0; r < 8; ++r) {
            const float4 hv = *reinterpret_cast<const float4*>(&bufB[(g * 8 + r) * 128 + kk]);
            a0[r] += hv.x * w00 + hv.y * w10 + hv.z * w20 + hv.w * w30;
            a1[r] += hv.x * w01 + hv.y * w11 + hv.z * w21 + hv.w * w31;
        }
    }
    const float bg10 = bg1[c2], bg11 = bg1[c2 + 1];
#pragma unroll
    for (int r = 0; r < 8; ++r) {
        float v0 = a0[r] + bg10;
        float v1 = a1[r] + bg11;
        bufA[(g * 8 + r) * 128 + c2]     = v0 / (1.f + __expf(-v0));
        bufA[(g * 8 + r) * 128 + c2 + 1] = v1 / (1.f + __expf(-v1));
    }
    __syncthreads();
    // gate = tanh(g1 @ wg2 + bg2); x_out = x + gate * disp
    {
        const int r = t >> 3, j = t & 7;
        float partial = 0.f;
        for (int cc = j; cc < 128; cc += 8) partial += bufA[r * 128 + cc] * wg2[cc];
        partial += __shfl_xor(partial, 1);
        partial += __shfl_xor(partial, 2);
        partial += __shfl_xor(partial, 4);
        const float gate = tanhf(partial + bg2[0]);
        if (j < 3) {
            const int row = row0 + r;
            xout[(size_t)row * 3 + j] = x[(size_t)row * 3 + j] + gate * disp[(size_t)row * 3 + j];
        }
    }
}

// ---------------------------------------------------------------- launcher

extern "C" void kernel_launch(void* const* d_in, const int* in_sizes, int n_in,
                              void* d_out, int out_size, void* d_ws, size_t ws_size,
                              hipStream_t stream) {
    const float* h     = (const float*)d_in[0];
    const float* x     = (const float*)d_in[1];
    const int*   src   = (const int*)d_in[2];
    const int*   dst   = (const int*)d_in[3];
    const float* dist  = (const float*)d_in[4];
    const float* bpp   = (const float*)d_in[5];
    const float* msa   = (const float*)d_in[6];
    const float* chem  = (const float*)d_in[7];
    const float* rel   = (const float*)d_in[8];
    const float* chain = (const float*)d_in[9];
    const float* Wq = (const float*)d_in[10];
    const float* Wk = (const float*)d_in[11];
    const float* Wv = (const float*)d_in[12];
    const float* Wo = (const float*)d_in[13];
    const float* bq = (const float*)d_in[14];
    const float* bk = (const float*)d_in[15];
    const float* bv = (const float*)d_in[16];
    const float* bo = (const float*)d_in[17];
    const float* w_dist = (const float*)d_in[18];  const float* b_dist = (const float*)d_in[19];
    const float* w_bpp  = (const float*)d_in[20];  const float* b_bpp  = (const float*)d_in[21];
    const float* w_msa  = (const float*)d_in[22];  const float* b_msa  = (const float*)d_in[23];
    const float* w_chem = (const float*)d_in[24];  const float* b_chem = (const float*)d_in[25];
    const float* w_rel  = (const float*)d_in[26];  const float* b_rel  = (const float*)d_in[27];
    const float* w_chain= (const float*)d_in[28];  const float* b_chain= (const float*)d_in[29];
    const float* Wg1 = (const float*)d_in[30];
    const float* bg1 = (const float*)d_in[31];
    const float* wg2 = (const float*)d_in[32];
    const float* bg2 = (const float*)d_in[33];

    float* fws   = (float*)d_ws;
    float* q     = fws;                           // N*128 f32
    float* hu    = q + (size_t)N_NODES * HID;     // N*128 f32
    float* biasS = hu + (size_t)N_NODES * HID;    // E*8 f32
    float* disp  = biasS + (size_t)N_EDGES * 8;   // N*3 f32
    __hip_bfloat16* k_bf = (__hip_bfloat16*)(disp + (size_t)N_NODES * 3);  // N*128 bf16
    __hip_bfloat16* v_bf = k_bf + (size_t)N_NODES * HID;                   // N*128 bf16
    int* dstS    = (int*)(v_bf + (size_t)N_NODES * HID);  // E
    int* startp  = dstS + N_EDGES;                // N (local scans)
    int* cnt     = startp + N_NODES;              // N
    int* blockSums = cnt + N_NODES;               // NB_SCAN+1

    float* hout = (float*)d_out;
    float* xout = hout + (size_t)N_NODES * HID;

    hipMemsetAsync(cnt, 0, (size_t)N_NODES * sizeof(int), stream);
    hipLaunchKernelGGL(hist_kernel, dim3(N_EDGES / 256), dim3(256), 0, stream, src, cnt);
    hipLaunchKernelGGL(scan1_kernel, dim3(NB_SCAN), dim3(256), 0, stream,
                       cnt, startp, blockSums, N_NODES);
    hipLaunchKernelGGL(scan2_kernel, dim3(1), dim3(128), 0, stream, blockSums, NB_SCAN);
    hipLaunchKernelGGL(scatter_kernel, dim3(N_EDGES / 256), dim3(256), 0, stream,
                       src, dst, dist, bpp, msa, chem, rel, chain,
                       w_dist, b_dist, w_bpp, b_bpp, w_msa, b_msa,
                       w_chem, b_chem, w_rel, b_rel, w_chain, b_chain,
                       startp, blockSums, cnt, dstS, biasS);
    hipLaunchKernelGGL(qkv_kernel, dim3(N_NODES / 32), dim3(256), 0, stream,
                       h, Wq, Wk, Wv, bq, bk, bv, q, k_bf, v_bf);
    hipLaunchKernelGGL(node_kernel, dim3(N_NODES / 4), dim3(256), 0, stream,
                       q, (const ushort*)k_bf, (const ushort*)v_bf, x, biasS,
                       dstS, startp, blockSums, hu, disp);
    hipLaunchKernelGGL(out_kernel, dim3(N_NODES / 32), dim3(256), 0, stream,
                       h, x, hu, Wo, bo, Wg1, bg1, wg2, bg2, disp, hout, xout);
}

// Round 5
// 208.706 us; speedup vs baseline: 1.7300x; 1.0751x over previous
//
#include <hip/hip_runtime.h>
#include <hip/hip_bf16.h>

#define N_NODES 20000
#define N_EDGES 640000
#define HID 128
#define HEADS 8
#define HD 16
#define NB_SCAN ((N_NODES + 255) / 256)   // 79
#define CH 160                            // edges per chunk (covers 4-node union ~99.8%)

typedef __attribute__((ext_vector_type(8))) short bf16x8;
typedef __attribute__((ext_vector_type(4))) float f32x4;

__device__ __forceinline__ float bflo(unsigned u) {
    union { unsigned i; float f; } x; x.i = u << 16; return x.f;
}
__device__ __forceinline__ float bfhi(unsigned u) {
    union { unsigned i; float f; } x; x.i = u & 0xffff0000u; return x.f;
}
__device__ __forceinline__ float bfu(ushort u) {
    union { unsigned i; float f; } x; x.i = ((unsigned)u) << 16; return x.f;
}
__device__ __forceinline__ ushort f2bu(float f) {
    __hip_bfloat16 b = __float2bfloat16(f);
    union { __hip_bfloat16 b; ushort u; } c; c.b = b; return c.u;
}

// ---------------------------------------------------------------- utilities

__global__ void hist_kernel(const int* __restrict__ src, int* __restrict__ cnt) {
    int e = blockIdx.x * 256 + threadIdx.x;
    if (e < N_EDGES) atomicAdd(&cnt[src[e]], 1);
}

__global__ __launch_bounds__(256) void scan1_kernel(int* __restrict__ cnt,
        int* __restrict__ startp, int* __restrict__ blockSums, int n) {
    __shared__ int sd[256];
    const int tid = threadIdx.x;
    const int i = blockIdx.x * 256 + tid;
    int xv = (i < n) ? cnt[i] : 0;
    sd[tid] = xv;
    __syncthreads();
#pragma unroll
    for (int off = 1; off < 256; off <<= 1) {
        int tv = (tid >= off) ? sd[tid - off] : 0;
        __syncthreads();
        sd[tid] += tv;
        __syncthreads();
    }
    if (i < n) { startp[i] = sd[tid] - xv; cnt[i] = 0; }
    if (tid == 255) blockSums[blockIdx.x] = sd[255];
}

__global__ __launch_bounds__(128) void scan2_kernel(int* __restrict__ blockSums, int nb) {
    __shared__ int sd[128];
    const int tid = threadIdx.x;
    int xv = (tid < nb) ? blockSums[tid] : 0;
    sd[tid] = xv;
    __syncthreads();
#pragma unroll
    for (int off = 1; off < 128; off <<= 1) {
        int tv = (tid >= off) ? sd[tid - off] : 0;
        __syncthreads();
        sd[tid] += tv;
        __syncthreads();
    }
    if (tid < nb) blockSums[tid] = sd[tid] - xv;
    if (tid == 127) blockSums[nb] = sd[127];
}

// transpose + bf16-cast the five 128x128 weight mats: Wt[m][n][k] = W[k][n]
__global__ __launch_bounds__(256) void prep_kernel(const float* __restrict__ Wq,
        const float* __restrict__ Wk, const float* __restrict__ Wv,
        const float* __restrict__ Wo, const float* __restrict__ Wg1,
        ushort* __restrict__ Wt) {
    const float* srcs[5] = {Wq, Wk, Wv, Wo, Wg1};
    const float* W = srcs[blockIdx.x];
    ushort* out = Wt + (size_t)blockIdx.x * 16384;
    for (int i = threadIdx.x; i < 16384; i += 256) {
        int k = i >> 7, n = i & 127;
        out[n * 128 + k] = f2bu(W[i]);
    }
}

// scatter edges into src-sorted order; pre-bake the 6 edge-bias heads (bf16)
__global__ void scatter_kernel(const int* __restrict__ src, const int* __restrict__ dst,
                               const float* __restrict__ dist, const float* __restrict__ bpp,
                               const float* __restrict__ msa, const float* __restrict__ chem,
                               const float* __restrict__ rel, const float* __restrict__ chain,
                               const float* __restrict__ w_dist, const float* __restrict__ b_dist,
                               const float* __restrict__ w_bpp, const float* __restrict__ b_bpp,
                               const float* __restrict__ w_msa, const float* __restrict__ b_msa,
                               const float* __restrict__ w_chem, const float* __restrict__ b_chem,
                               const float* __restrict__ w_rel, const float* __restrict__ b_rel,
                               const float* __restrict__ w_chain, const float* __restrict__ b_chain,
                               const int* __restrict__ startp, const int* __restrict__ blockSums,
                               int* __restrict__ cnt,
                               int* __restrict__ dstS, ushort* __restrict__ biasb) {
    int e = blockIdx.x * 256 + threadIdx.x;
    if (e >= N_EDGES) return;
    int s = src[e];
    int pos = startp[s] + blockSums[s >> 8] + atomicAdd(&cnt[s], 1);
    dstS[pos] = dst[e];
    float d2 = dist[e] * dist[e];
    float f_bpp = bpp[e], f_msa = msa[e], f_chem = chem[e], f_rel = rel[e], f_chain = chain[e];
    ushort o16[8];
#pragma unroll
    for (int h = 0; h < 8; ++h) {
        float b = -(d2 * w_dist[h] + b_dist[h])
                + (f_bpp * w_bpp[h] + b_bpp[h])
                + (f_msa * w_msa[h] + b_msa[h])
                + (f_chem * w_chem[h] + b_chem[h])
                + (f_rel * w_rel[h] + b_rel[h])
                + (f_chain * w_chain[h] + b_chain[h]);
        o16[h] = f2bu(b);
    }
    uint4 pk;
    pk.x = (unsigned)o16[0] | ((unsigned)o16[1] << 16);
    pk.y = (unsigned)o16[2] | ((unsigned)o16[3] << 16);
    pk.z = (unsigned)o16[4] | ((unsigned)o16[5] << 16);
    pk.w = (unsigned)o16[6] | ((unsigned)o16[7] << 16);
    *reinterpret_cast<uint4*>(biasb + (size_t)pos * 8) = pk;
}

// ------------------------------------------------------------- q,k,v GEMMs (MFMA)
// 32-row tile, 4 waves; wave: row-tile rt=w>>1, col-tiles (2*ctp + (w&1)), 3 mats.
// A: lane row=lane&15, k=(lane>>4)*8+i ; B(Wt[n][k]): col=lane&15, same k
// D: col=lane&15, row=(lane>>4)*4+r  (measured m89)
__global__ __launch_bounds__(256) void qkv_kernel(const float* __restrict__ h,
        const ushort* __restrict__ Wt,
        const float* __restrict__ bq, const float* __restrict__ bk, const float* __restrict__ bv,
        ushort* __restrict__ qb, ushort* __restrict__ kb, ushort* __restrict__ vb) {
    __shared__ __align__(16) ushort hs[32 * 136];
    const int t = threadIdx.x;
    const int row0 = blockIdx.x * 32;
    for (int i = t; i < 4096; i += 256)
        hs[(i >> 7) * 136 + (i & 127)] = f2bu(h[(size_t)row0 * 128 + i]);
    __syncthreads();
    const int w = t >> 6, lane = t & 63;
    const int rt = w >> 1, half = w & 1;
    const int lrow = lane & 15, lkb = (lane >> 4) * 8;
    bf16x8 a[4];
#pragma unroll
    for (int ks = 0; ks < 4; ++ks)
        a[ks] = *reinterpret_cast<const bf16x8*>(&hs[(rt * 16 + lrow) * 136 + ks * 32 + lkb]);
    const int rbase = row0 + rt * 16 + (lane >> 4) * 4;

#define DO_MAT(MI, BIAS, OUT) \
    for (int ctp = 0; ctp < 4; ++ctp) { \
        const int col = (ctp * 2 + half) * 16 + lrow; \
        f32x4 acc = {0.f, 0.f, 0.f, 0.f}; \
        _Pragma("unroll") \
        for (int ks = 0; ks < 4; ++ks) { \
            bf16x8 b = *reinterpret_cast<const bf16x8*>(&Wt[MI * 16384 + col * 128 + ks * 32 + lkb]); \
            acc = __builtin_amdgcn_mfma_f32_16x16x32_bf16(a[ks], b, acc, 0, 0, 0); \
        } \
        const float bias = BIAS[col]; \
        _Pragma("unroll") \
        for (int r = 0; r < 4; ++r) \
            OUT[(size_t)(rbase + r) * 128 + col] = f2bu(acc[r] + bias); \
    }
    DO_MAT(0, bq, qb)
    DO_MAT(1, bk, kb)
    DO_MAT(2, bv, vb)
#undef DO_MAT
}

// --------------------------------------------- per-node fused softmax + agg
__global__ __launch_bounds__(256) void node_kernel(const ushort* __restrict__ qb,
        const ushort* __restrict__ k_bf, const ushort* __restrict__ v_bf,
        const float* __restrict__ x, const ushort* __restrict__ biasb,
        const int* __restrict__ dstS, const int* __restrict__ startp,
        const int* __restrict__ blockSums,
        ushort* __restrict__ hub, float* __restrict__ disp) {
    __shared__ float qLds[4 * 128];
    __shared__ float xsLds[12];
    __shared__ int   sLds[5];
    __shared__ int   dnLds[CH];
    __shared__ float xLds[CH * 3 + 4];
    __shared__ float peLds[CH * 8];
    __shared__ float redLds[4 * 256];
    __shared__ float denLds[256];
    __shared__ float adxLds[256];
    __shared__ float dpLds[32];

    const int t = threadIdx.x;
    const int n0 = blockIdx.x * 4;

    for (int i = t; i < 4 * 128; i += 256) qLds[i] = bfu(qb[(size_t)n0 * 128 + i]);
    if (t < 12) xsLds[t] = x[(size_t)n0 * 3 + t];
    if (t < 5) {
        int idx = n0 + t;
        sLds[t] = (idx < N_NODES) ? (startp[idx] + blockSums[idx >> 8]) : N_EDGES;
    }
    __syncthreads();

    const int S0 = sLds[0], S4 = sLds[4];
    const int s1r = sLds[1], s2r = sLds[2], s3r = sLds[3];

    const int eg = t >> 5;          // 0..7 edge-group
    const int dq = t & 31;          // dim-quad: dims 4dq..4dq+3
    const int hh = dq >> 2;         // head
    const int jj = dq & 3;
    const int j3 = (jj < 3) ? jj : 0;

    float acc0[4] = {0,0,0,0}, acc1[4] = {0,0,0,0};
    float acc2[4] = {0,0,0,0}, acc3[4] = {0,0,0,0};
    float den0 = 0, den1 = 0, den2 = 0, den3 = 0;
    float adx0 = 0, adx1 = 0, adx2 = 0, adx3 = 0;

    for (int base = S0; base < S4; base += CH) {
        const int en = min(CH, S4 - base);
        __syncthreads();
        if (t < en) {
            int dn = dstS[base + t];
            dnLds[t] = dn;
            xLds[t * 3 + 0] = x[(size_t)dn * 3 + 0];
            xLds[t * 3 + 1] = x[(size_t)dn * 3 + 1];
            xLds[t * 3 + 2] = x[(size_t)dn * 3 + 2];
        }
        __syncthreads();
        // ---- phase A: exp-logits for (edge, head) pairs ----
        const int np = en * 8;
        for (int p = t; p < np; p += 256) {
            const int e = p >> 3, ha = p & 7;
            const int ge = base + e;
            const int m = (ge >= s1r) + (ge >= s2r) + (ge >= s3r);
            const ushort* krow = k_bf + (size_t)dnLds[e] * 128 + ha * 16;
            const uint4 ka = *reinterpret_cast<const uint4*>(krow);
            const uint4 kb4 = *reinterpret_cast<const uint4*>(krow + 8);
            const float* qrow = &qLds[m * 128 + ha * 16];
            const unsigned* kau = reinterpret_cast<const unsigned*>(&ka);
            const unsigned* kbu = reinterpret_cast<const unsigned*>(&kb4);
            float s = 0.f;
#pragma unroll
            for (int i = 0; i < 4; ++i) {
                s += bflo(kau[i]) * qrow[2 * i]     + bfhi(kau[i]) * qrow[2 * i + 1];
                s += bflo(kbu[i]) * qrow[8 + 2 * i] + bfhi(kbu[i]) * qrow[8 + 2 * i + 1];
            }
            peLds[p] = __expf(fmaf(s, 0.25f, bfu(biasb[(size_t)ge * 8 + ha])));
        }
        __syncthreads();
        // ---- phase C: per-node gather-accumulate ----
#define NODE_C(M, ACC, DEN, ADX) { \
            const int lo = max(sLds[M] - base, 0); \
            const int hi = min(sLds[M + 1] - base, en); \
            const float xsv = xsLds[M * 3 + j3]; \
            for (int e = lo + eg; e < hi; e += 8) { \
                const float pe = peLds[e * 8 + hh]; \
                const ushort4 vv = *reinterpret_cast<const ushort4*>( \
                    v_bf + (size_t)dnLds[e] * 128 + dq * 4); \
                ACC[0] = fmaf(pe, bfu(vv.x), ACC[0]); \
                ACC[1] = fmaf(pe, bfu(vv.y), ACC[1]); \
                ACC[2] = fmaf(pe, bfu(vv.z), ACC[2]); \
                ACC[3] = fmaf(pe, bfu(vv.w), ACC[3]); \
                DEN += pe; \
                ADX = fmaf(pe, xLds[e * 3 + j3] - xsv, ADX); \
            } }
        NODE_C(0, acc0, den0, adx0)
        NODE_C(1, acc1, den1, adx1)
        NODE_C(2, acc2, den2, adx2)
        NODE_C(3, acc3, den3, adx3)
#undef NODE_C
    }

#define REDUCE_M(M, ACC, DEN, ADX) { \
        redLds[0 * 256 + t] = ACC[0]; redLds[1 * 256 + t] = ACC[1]; \
        redLds[2 * 256 + t] = ACC[2]; redLds[3 * 256 + t] = ACC[3]; \
        denLds[t] = DEN; adxLds[t] = ADX; \
        __syncthreads(); \
        if (t < 128) { \
            const int dqr = t >> 2, jr = t & 3, hr = t >> 4; \
            float s = 0.f, dsum = 0.f; \
            _Pragma("unroll") \
            for (int gg = 0; gg < 8; ++gg) { \
                s += redLds[jr * 256 + gg * 32 + dqr]; \
                dsum += denLds[gg * 32 + hr * 4]; \
            } \
            hub[(size_t)(n0 + M) * 128 + t] = f2bu(s / fmaxf(dsum, 1e-9f)); \
        } \
        if (t < 32 && jj < 3) { \
            float s = 0.f, dsum = 0.f; \
            _Pragma("unroll") \
            for (int gg = 0; gg < 8; ++gg) { \
                s += adxLds[gg * 32 + hh * 4 + jj]; \
                dsum += denLds[gg * 32 + hh * 4]; \
            } \
            dpLds[hh * 4 + jj] = s / fmaxf(dsum, 1e-9f); \
        } \
        __syncthreads(); \
        if (t < 3) { \
            float s = 0.f; \
            _Pragma("unroll") \
            for (int hq = 0; hq < 8; ++hq) s += dpLds[hq * 4 + t]; \
            disp[(size_t)(n0 + M) * 3 + t] = s * 0.125f; \
        } }
    REDUCE_M(0, acc0, den0, adx0)
    __syncthreads();
    REDUCE_M(1, acc1, den1, adx1)
    __syncthreads();
    REDUCE_M(2, acc2, den2, adx2)
    __syncthreads();
    REDUCE_M(3, acc3, den3, adx3)
#undef REDUCE_M
}

// --------------------- fused output GEMM + gate MLP + coords (MFMA)
__global__ __launch_bounds__(256) void out_kernel(const float* __restrict__ h,
        const float* __restrict__ x, const ushort* __restrict__ hub,
        const ushort* __restrict__ Wt,
        const float* __restrict__ bo, const float* __restrict__ bg1,
        const float* __restrict__ wg2, const float* __restrict__ bg2,
        const float* __restrict__ disp,
        float* __restrict__ hout, float* __restrict__ xout) {
    __shared__ __align__(16) ushort hus[32 * 136];
    __shared__ __align__(16) ushort hob[32 * 136];
    __shared__ float g1s[32 * 132];
    const int t = threadIdx.x;
    const int row0 = blockIdx.x * 32;
    for (int i = t; i < 4096; i += 256)
        hus[(i >> 7) * 136 + (i & 127)] = hub[(size_t)row0 * 128 + i];
    __syncthreads();
    const int w = t >> 6, lane = t & 63;
    const int rt = w >> 1, half = w & 1;
    const int lrow = lane & 15, lkb = (lane >> 4) * 8;
    const int rloc = rt * 16 + (lane >> 4) * 4;
    bf16x8 a[4];
#pragma unroll
    for (int ks = 0; ks < 4; ++ks)
        a[ks] = *reinterpret_cast<const bf16x8*>(&hus[(rt * 16 + lrow) * 136 + ks * 32 + lkb]);
    // ---- stage 1: h_out = h + hu @ Wo + bo ----
    for (int ctp = 0; ctp < 4; ++ctp) {
        const int col = (ctp * 2 + half) * 16 + lrow;
        f32x4 acc = {0.f, 0.f, 0.f, 0.f};
#pragma unroll
        for (int ks = 0; ks < 4; ++ks) {
            bf16x8 b = *reinterpret_cast<const bf16x8*>(&Wt[3 * 16384 + col * 128 + ks * 32 + lkb]);
            acc = __builtin_amdgcn_mfma_f32_16x16x32_bf16(a[ks], b, acc, 0, 0, 0);
        }
        const float bias = bo[col];
#pragma unroll
        for (int r = 0; r < 4; ++r) {
            const int row = rloc + r;
            float hv = h[(size_t)(row0 + row) * 128 + col] + acc[r] + bias;
            hout[(size_t)(row0 + row) * 128 + col] = hv;
            hob[row * 136 + col] = f2bu(hv);
        }
    }
    __syncthreads();
    // ---- stage 2: g1 = silu(h_out @ Wg1 + bg1) ----
#pragma unroll
    for (int ks = 0; ks < 4; ++ks)
        a[ks] = *reinterpret_cast<const bf16x8*>(&hob[(rt * 16 + lrow) * 136 + ks * 32 + lkb]);
    for (int ctp = 0; ctp < 4; ++ctp) {
        const int col = (ctp * 2 + half) * 16 + lrow;
        f32x4 acc = {0.f, 0.f, 0.f, 0.f};
#pragma unroll
        for (int ks = 0; ks < 4; ++ks) {
            bf16x8 b = *reinterpret_cast<const bf16x8*>(&Wt[4 * 16384 + col * 128 + ks * 32 + lkb]);
            acc = __builtin_amdgcn_mfma_f32_16x16x32_bf16(a[ks], b, acc, 0, 0, 0);
        }
        const float bias = bg1[col];
#pragma unroll
        for (int r = 0; r < 4; ++r) {
            float av = acc[r] + bias;
            g1s[(rloc + r) * 132 + col] = av / (1.f + __expf(-av));
        }
    }
    __syncthreads();
    // ---- stage 3: gate = tanh(g1 @ wg2 + bg2); x_out ----
    {
        const int r = t >> 3, j = t & 7;
        float partial = 0.f;
        for (int cc = j; cc < 128; cc += 8) partial += g1s[r * 132 + cc] * wg2[cc];
        partial += __shfl_xor(partial, 1);
        partial += __shfl_xor(partial, 2);
        partial += __shfl_xor(partial, 4);
        const float gate = tanhf(partial + bg2[0]);
        if (j < 3) {
            const int row = row0 + r;
            xout[(size_t)row * 3 + j] = x[(size_t)row * 3 + j] + gate * disp[(size_t)row * 3 + j];
        }
    }
}

// ---------------------------------------------------------------- launcher

extern "C" void kernel_launch(void* const* d_in, const int* in_sizes, int n_in,
                              void* d_out, int out_size, void* d_ws, size_t ws_size,
                              hipStream_t stream) {
    const float* h     = (const float*)d_in[0];
    const float* x     = (const float*)d_in[1];
    const int*   src   = (const int*)d_in[2];
    const int*   dst   = (const int*)d_in[3];
    const float* dist  = (const float*)d_in[4];
    const float* bpp   = (const float*)d_in[5];
    const float* msa   = (const float*)d_in[6];
    const float* chem  = (const float*)d_in[7];
    const float* rel   = (const float*)d_in[8];
    const float* chain = (const float*)d_in[9];
    const float* Wq = (const float*)d_in[10];
    const float* Wk = (const float*)d_in[11];
    const float* Wv = (const float*)d_in[12];
    const float* Wo = (const float*)d_in[13];
    const float* bq = (const float*)d_in[14];
    const float* bk = (const float*)d_in[15];
    const float* bv = (const float*)d_in[16];
    const float* bo = (const float*)d_in[17];
    const float* w_dist = (const float*)d_in[18];  const float* b_dist = (const float*)d_in[19];
    const float* w_bpp  = (const float*)d_in[20];  const float* b_bpp  = (const float*)d_in[21];
    const float* w_msa  = (const float*)d_in[22];  const float* b_msa  = (const float*)d_in[23];
    const float* w_chem = (const float*)d_in[24];  const float* b_chem = (const float*)d_in[25];
    const float* w_rel  = (const float*)d_in[26];  const float* b_rel  = (const float*)d_in[27];
    const float* w_chain= (const float*)d_in[28];  const float* b_chain= (const float*)d_in[29];
    const float* Wg1 = (const float*)d_in[30];
    const float* bg1 = (const float*)d_in[31];
    const float* wg2 = (const float*)d_in[32];
    const float* bg2 = (const float*)d_in[33];

    char* wp = (char*)d_ws;
    const size_t NH2 = (size_t)N_NODES * HID * sizeof(ushort);   // 5,120,000
    ushort* hub   = (ushort*)wp;               wp += NH2;
    ushort* qb    = (ushort*)wp;               wp += NH2;
    ushort* kb    = (ushort*)wp;               wp += NH2;
    ushort* vb    = (ushort*)wp;               wp += NH2;
    ushort* biasb = (ushort*)wp;               wp += (size_t)N_EDGES * 8 * sizeof(ushort);
    float*  disp  = (float*)wp;                wp += (size_t)N_NODES * 3 * sizeof(float);
    int* dstS     = (int*)wp;                  wp += (size_t)N_EDGES * sizeof(int);
    int* startp   = (int*)wp;                  wp += (size_t)N_NODES * sizeof(int);
    int* cnt      = (int*)wp;                  wp += (size_t)N_NODES * sizeof(int);
    int* blockSums= (int*)wp;                  wp += (size_t)(NB_SCAN + 1) * sizeof(int);
    ushort* Wt    = (ushort*)wp;               wp += (size_t)5 * 16384 * sizeof(ushort);

    float* hout = (float*)d_out;
    float* xout = hout + (size_t)N_NODES * HID;

    hipMemsetAsync(cnt, 0, (size_t)N_NODES * sizeof(int), stream);
    hipLaunchKernelGGL(prep_kernel, dim3(5), dim3(256), 0, stream, Wq, Wk, Wv, Wo, Wg1, Wt);
    hipLaunchKernelGGL(hist_kernel, dim3(N_EDGES / 256), dim3(256), 0, stream, src, cnt);
    hipLaunchKernelGGL(scan1_kernel, dim3(NB_SCAN), dim3(256), 0, stream,
                       cnt, startp, blockSums, N_NODES);
    hipLaunchKernelGGL(scan2_kernel, dim3(1), dim3(128), 0, stream, blockSums, NB_SCAN);
    hipLaunchKernelGGL(scatter_kernel, dim3(N_EDGES / 256), dim3(256), 0, stream,
                       src, dst, dist, bpp, msa, chem, rel, chain,
                       w_dist, b_dist, w_bpp, b_bpp, w_msa, b_msa,
                       w_chem, b_chem, w_rel, b_rel, w_chain, b_chain,
                       startp, blockSums, cnt, dstS, biasb);
    hipLaunchKernelGGL(qkv_kernel, dim3(N_NODES / 32), dim3(256), 0, stream,
                       h, Wt, bq, bk, bv, qb, kb, vb);
    hipLaunchKernelGGL(node_kernel, dim3(N_NODES / 4), dim3(256), 0, stream,
                       qb, kb, vb, x, biasb, dstS, startp, blockSums, hub, disp);
    hipLaunchKernelGGL(out_kernel, dim3(N_NODES / 32), dim3(256), 0, stream,
                       h, x, hub, Wt, bo, bg1, wg2, bg2, disp, hout, xout);
}

// Round 6
// 163.824 us; speedup vs baseline: 2.2039x; 1.2740x over previous
//
#include <hip/hip_runtime.h>
#include <hip/hip_bf16.h>

#define N_NODES 20000
#define N_EDGES 640000
#define HID 128
#define HEADS 8
#define HD 16
#define NB_SCAN ((N_NODES + 255) / 256)   // 79
#define CH 160                            // edges per chunk (covers 4-node union ~99.8%)
#define QKV_BLOCKS 625                    // 20000/32
#define PREP_BLOCKS 5

typedef __attribute__((ext_vector_type(8))) short bf16x8;
typedef __attribute__((ext_vector_type(4))) float f32x4;

__device__ __forceinline__ float bflo(unsigned u) {
    union { unsigned i; float f; } x; x.i = u << 16; return x.f;
}
__device__ __forceinline__ float bfhi(unsigned u) {
    union { unsigned i; float f; } x; x.i = u & 0xffff0000u; return x.f;
}
__device__ __forceinline__ float bfu(ushort u) {
    union { unsigned i; float f; } x; x.i = ((unsigned)u) << 16; return x.f;
}
__device__ __forceinline__ ushort f2bu(float f) {
    __hip_bfloat16 b = __float2bfloat16(f);
    union { __hip_bfloat16 b; ushort u; } c; c.b = b; return c.u;
}

// ------------------------------------------- fused prep (weights) + hist+rank
__global__ __launch_bounds__(256) void hist_prep_kernel(const int* __restrict__ src,
        int* __restrict__ cnt, int* __restrict__ rank,
        const float* __restrict__ Wq, const float* __restrict__ Wk,
        const float* __restrict__ Wv, const float* __restrict__ Wo,
        const float* __restrict__ Wg1, ushort* __restrict__ Wt) {
    if (blockIdx.x < PREP_BLOCKS) {
        // transpose + bf16-cast one 128x128 weight matrix: Wt[m][n][k] = W[k][n]
        const float* srcs[5] = {Wq, Wk, Wv, Wo, Wg1};
        const float* W = srcs[blockIdx.x];
        ushort* out = Wt + (size_t)blockIdx.x * 16384;
        for (int i = threadIdx.x; i < 16384; i += 256) {
            int k = i >> 7, n = i & 127;
            out[n * 128 + k] = f2bu(W[i]);
        }
    } else {
        const int e = (blockIdx.x - PREP_BLOCKS) * 256 + threadIdx.x;
        rank[e] = atomicAdd(&cnt[src[e]], 1);
    }
}

__global__ __launch_bounds__(256) void scan1_kernel(const int* __restrict__ cnt,
        int* __restrict__ startp, int* __restrict__ blockSums, int n) {
    __shared__ int sd[256];
    const int tid = threadIdx.x;
    const int i = blockIdx.x * 256 + tid;
    int xv = (i < n) ? cnt[i] : 0;
    sd[tid] = xv;
    __syncthreads();
#pragma unroll
    for (int off = 1; off < 256; off <<= 1) {
        int tv = (tid >= off) ? sd[tid - off] : 0;
        __syncthreads();
        sd[tid] += tv;
        __syncthreads();
    }
    if (i < n) startp[i] = sd[tid] - xv;
    if (tid == 255) blockSums[blockIdx.x] = sd[255];
}

__global__ __launch_bounds__(128) void scan2_kernel(int* __restrict__ blockSums, int nb) {
    __shared__ int sd[128];
    const int tid = threadIdx.x;
    int xv = (tid < nb) ? blockSums[tid] : 0;
    sd[tid] = xv;
    __syncthreads();
#pragma unroll
    for (int off = 1; off < 128; off <<= 1) {
        int tv = (tid >= off) ? sd[tid - off] : 0;
        __syncthreads();
        sd[tid] += tv;
        __syncthreads();
    }
    if (tid < nb) blockSums[tid] = sd[tid] - xv;
    if (tid == 127) blockSums[nb] = sd[127];
}

// ------------------- fused: qkv MFMA GEMM (blocks 0..624)  ∥  edge scatter
// scatter: pos = start + rank (no atomic); writes 32B records
// {bias[8] bf16, dst int, x[dst] f32x3}
__global__ __launch_bounds__(256) void scatter_qkv_kernel(
        const float* __restrict__ h, const ushort* __restrict__ Wt,
        const float* __restrict__ bq, const float* __restrict__ bk,
        const float* __restrict__ bv,
        ushort* __restrict__ qb, ushort* __restrict__ kb, ushort* __restrict__ vb,
        const int* __restrict__ src, const int* __restrict__ dst,
        const float* __restrict__ dist, const float* __restrict__ bpp,
        const float* __restrict__ msa, const float* __restrict__ chem,
        const float* __restrict__ rel, const float* __restrict__ chain,
        const float* __restrict__ w_dist, const float* __restrict__ b_dist,
        const float* __restrict__ w_bpp, const float* __restrict__ b_bpp,
        const float* __restrict__ w_msa, const float* __restrict__ b_msa,
        const float* __restrict__ w_chem, const float* __restrict__ b_chem,
        const float* __restrict__ w_rel, const float* __restrict__ b_rel,
        const float* __restrict__ w_chain, const float* __restrict__ b_chain,
        const int* __restrict__ startp, const int* __restrict__ blockSums,
        const int* __restrict__ rank, const float* __restrict__ x,
        uint4* __restrict__ recs) {
    __shared__ __align__(16) ushort hs[32 * 136];
    const int t = threadIdx.x;
    if (blockIdx.x < QKV_BLOCKS) {
        const int row0 = blockIdx.x * 32;
        for (int i = t; i < 4096; i += 256)
            hs[(i >> 7) * 136 + (i & 127)] = f2bu(h[(size_t)row0 * 128 + i]);
        __syncthreads();
        const int w = t >> 6, lane = t & 63;
        const int rt = w >> 1, half = w & 1;
        const int lrow = lane & 15, lkb = (lane >> 4) * 8;
        bf16x8 a[4];
#pragma unroll
        for (int ks = 0; ks < 4; ++ks)
            a[ks] = *reinterpret_cast<const bf16x8*>(&hs[(rt * 16 + lrow) * 136 + ks * 32 + lkb]);
        const int rbase = row0 + rt * 16 + (lane >> 4) * 4;
#define DO_MAT(MI, BIAS, OUT) \
        for (int ctp = 0; ctp < 4; ++ctp) { \
            const int col = (ctp * 2 + half) * 16 + lrow; \
            f32x4 acc = {0.f, 0.f, 0.f, 0.f}; \
            _Pragma("unroll") \
            for (int ks = 0; ks < 4; ++ks) { \
                bf16x8 b = *reinterpret_cast<const bf16x8*>( \
                    &Wt[MI * 16384 + col * 128 + ks * 32 + lkb]); \
                acc = __builtin_amdgcn_mfma_f32_16x16x32_bf16(a[ks], b, acc, 0, 0, 0); \
            } \
            const float bias = BIAS[col]; \
            _Pragma("unroll") \
            for (int r = 0; r < 4; ++r) \
                OUT[(size_t)(rbase + r) * 128 + col] = f2bu(acc[r] + bias); \
        }
        DO_MAT(0, bq, qb)
        DO_MAT(1, bk, kb)
        DO_MAT(2, bv, vb)
#undef DO_MAT
    } else {
        const int e = (blockIdx.x - QKV_BLOCKS) * 256 + t;
        const int s = src[e];
        const int pos = startp[s] + blockSums[s >> 8] + rank[e];
        const int dn = dst[e];
        const float d2 = dist[e] * dist[e];
        const float f_bpp = bpp[e], f_msa = msa[e], f_chem = chem[e];
        const float f_rel = rel[e], f_chain = chain[e];
        ushort o16[8];
#pragma unroll
        for (int hq = 0; hq < 8; ++hq) {
            float b = -(d2 * w_dist[hq] + b_dist[hq])
                    + (f_bpp * w_bpp[hq] + b_bpp[hq])
                    + (f_msa * w_msa[hq] + b_msa[hq])
                    + (f_chem * w_chem[hq] + b_chem[hq])
                    + (f_rel * w_rel[hq] + b_rel[hq])
                    + (f_chain * w_chain[hq] + b_chain[hq]);
            o16[hq] = f2bu(b);
        }
        uint4 rec0;
        rec0.x = (unsigned)o16[0] | ((unsigned)o16[1] << 16);
        rec0.y = (unsigned)o16[2] | ((unsigned)o16[3] << 16);
        rec0.z = (unsigned)o16[4] | ((unsigned)o16[5] << 16);
        rec0.w = (unsigned)o16[6] | ((unsigned)o16[7] << 16);
        const float* xp = &x[(size_t)dn * 3];
        uint4 rec1;
        rec1.x = (unsigned)dn;
        rec1.y = __float_as_uint(xp[0]);
        rec1.z = __float_as_uint(xp[1]);
        rec1.w = __float_as_uint(xp[2]);
        recs[(size_t)pos * 2]     = rec0;
        recs[(size_t)pos * 2 + 1] = rec1;
    }
}

// --------------------------------------------- per-node fused softmax + agg
__global__ __launch_bounds__(256) void node_kernel(const ushort* __restrict__ qb,
        const ushort* __restrict__ kb, const ushort* __restrict__ vb,
        const uint4* __restrict__ recs, const float* __restrict__ x,
        const int* __restrict__ startp, const int* __restrict__ blockSums,
        ushort* __restrict__ hub, float* __restrict__ disp) {
    __shared__ float qLds[4 * 128];
    __shared__ float xsLds[12];
    __shared__ int   sLds[5];
    __shared__ int   dnLds[CH];
    __shared__ float xLds[CH * 3];
    __shared__ __align__(16) ushort biasLds[CH * 8];
    __shared__ float peLds[CH * 8];
    __shared__ float redN[4][32][9];

    const int t = threadIdx.x;
    const int n0 = blockIdx.x * 4;

    for (int i = t; i < 4 * 128; i += 256) qLds[i] = bfu(qb[(size_t)n0 * 128 + i]);
    if (t < 12) xsLds[t] = x[(size_t)n0 * 3 + t];
    if (t < 5) {
        int idx = n0 + t;
        sLds[t] = (idx < N_NODES) ? (startp[idx] + blockSums[idx >> 8]) : N_EDGES;
    }
    __syncthreads();

    const int S0 = sLds[0], S4 = sLds[4];
    const int s1r = sLds[1], s2r = sLds[2], s3r = sLds[3];

    const int eg = t >> 5;          // 0..7 edge-group
    const int dq = t & 31;          // dim-quad: dims 4dq..4dq+3
    const int hh = dq >> 2;         // head
    const int jj = dq & 3;
    const int j3 = (jj < 3) ? jj : 0;

    float acc0[4] = {0,0,0,0}, acc1[4] = {0,0,0,0};
    float acc2[4] = {0,0,0,0}, acc3[4] = {0,0,0,0};
    float den0 = 0, den1 = 0, den2 = 0, den3 = 0;
    float adx0 = 0, adx1 = 0, adx2 = 0, adx3 = 0;

    for (int base = S0; base < S4; base += CH) {
        const int en = min(CH, S4 - base);
        __syncthreads();
        if (t < en) {
            const uint4 r0 = recs[(size_t)(base + t) * 2];
            const uint4 r1 = recs[(size_t)(base + t) * 2 + 1];
            *reinterpret_cast<uint4*>(&biasLds[t * 8]) = r0;
            dnLds[t] = (int)r1.x;
            xLds[t * 3 + 0] = __uint_as_float(r1.y);
            xLds[t * 3 + 1] = __uint_as_float(r1.z);
            xLds[t * 3 + 2] = __uint_as_float(r1.w);
        }
        __syncthreads();
        // ---- phase A: exp-logits for (edge, head) pairs ----
        const int np = en * 8;
        for (int p = t; p < np; p += 256) {
            const int e = p >> 3, ha = p & 7;
            const int ge = base + e;
            const int m = (ge >= s1r) + (ge >= s2r) + (ge >= s3r);
            const ushort* krow = kb + (size_t)dnLds[e] * 128 + ha * 16;
            const uint4 ka = *reinterpret_cast<const uint4*>(krow);
            const uint4 kb4 = *reinterpret_cast<const uint4*>(krow + 8);
            const float* qrow = &qLds[m * 128 + ha * 16];
            const unsigned* kau = reinterpret_cast<const unsigned*>(&ka);
            const unsigned* kbu = reinterpret_cast<const unsigned*>(&kb4);
            float s = 0.f;
#pragma unroll
            for (int i = 0; i < 4; ++i) {
                s += bflo(kau[i]) * qrow[2 * i]     + bfhi(kau[i]) * qrow[2 * i + 1];
                s += bflo(kbu[i]) * qrow[8 + 2 * i] + bfhi(kbu[i]) * qrow[8 + 2 * i + 1];
            }
            peLds[p] = __expf(fmaf(s, 0.25f, bfu(biasLds[p])));
        }
        __syncthreads();
        // ---- phase C: per-node gather-accumulate ----
#define NODE_C(M, ACC, DEN, ADX) { \
            const int lo = max(sLds[M] - base, 0); \
            const int hi = min(sLds[M + 1] - base, en); \
            const float xsv = xsLds[M * 3 + j3]; \
            for (int e = lo + eg; e < hi; e += 8) { \
                const float pe = peLds[e * 8 + hh]; \
                const ushort4 vv = *reinterpret_cast<const ushort4*>( \
                    vb + (size_t)dnLds[e] * 128 + dq * 4); \
                ACC[0] = fmaf(pe, bfu(vv.x), ACC[0]); \
                ACC[1] = fmaf(pe, bfu(vv.y), ACC[1]); \
                ACC[2] = fmaf(pe, bfu(vv.z), ACC[2]); \
                ACC[3] = fmaf(pe, bfu(vv.w), ACC[3]); \
                DEN += pe; \
                ADX = fmaf(pe, xLds[e * 3 + j3] - xsv, ADX); \
            } }
        NODE_C(0, acc0, den0, adx0)
        NODE_C(1, acc1, den1, adx1)
        NODE_C(2, acc2, den2, adx2)
        NODE_C(3, acc3, den3, adx3)
#undef NODE_C
    }

    // ---- epilogue: shfl pre-reduce over eg pairs, light LDS reduce ----
    const int wv = t >> 6, lane = t & 63;
#define RED_M(M, ACC, DEN, ADX) { \
        float r0 = ACC[0], r1 = ACC[1], r2 = ACC[2], r3 = ACC[3]; \
        float rd = DEN, rx = (jj < 3) ? ADX : 0.f; \
        r0 += __shfl_xor(r0, 32); r1 += __shfl_xor(r1, 32); \
        r2 += __shfl_xor(r2, 32); r3 += __shfl_xor(r3, 32); \
        rd += __shfl_xor(rd, 32); rx += __shfl_xor(rx, 32); \
        if (lane < 32) { \
            redN[wv][lane][0] = r0; redN[wv][lane][1] = r1; \
            redN[wv][lane][2] = r2; redN[wv][lane][3] = r3; \
            redN[wv][lane][4] = rd; redN[wv][lane][5] = rx; \
        } \
        __syncthreads(); \
        if (t < 128) { \
            const int dqr = t >> 2, vi = t & 3; \
            float s = redN[0][dqr][vi] + redN[1][dqr][vi] \
                    + redN[2][dqr][vi] + redN[3][dqr][vi]; \
            float d = redN[0][dqr][4] + redN[1][dqr][4] \
                    + redN[2][dqr][4] + redN[3][dqr][4]; \
            hub[(size_t)(n0 + M) * 128 + t] = f2bu(s / fmaxf(d, 1e-9f)); \
        } \
        if (t < 32) { \
            float v = redN[0][t][5] + redN[1][t][5] + redN[2][t][5] + redN[3][t][5]; \
            float d = redN[0][t][4] + redN[1][t][4] + redN[2][t][4] + redN[3][t][4]; \
            float s = v / fmaxf(d, 1e-9f); \
            s += __shfl_xor(s, 4); s += __shfl_xor(s, 8); s += __shfl_xor(s, 16); \
            if (t < 3) disp[(size_t)(n0 + M) * 3 + t] = s * 0.125f; \
        } \
        __syncthreads(); }
    RED_M(0, acc0, den0, adx0)
    RED_M(1, acc1, den1, adx1)
    RED_M(2, acc2, den2, adx2)
    RED_M(3, acc3, den3, adx3)
#undef RED_M
}

// --------------------- fused output GEMM + gate MLP + coords (MFMA)
__global__ __launch_bounds__(256) void out_kernel(const float* __restrict__ h,
        const float* __restrict__ x, const ushort* __restrict__ hub,
        const ushort* __restrict__ Wt,
        const float* __restrict__ bo, const float* __restrict__ bg1,
        const float* __restrict__ wg2, const float* __restrict__ bg2,
        const float* __restrict__ disp,
        float* __restrict__ hout, float* __restrict__ xout) {
    __shared__ __align__(16) ushort hus[32 * 136];
    __shared__ __align__(16) ushort hob[32 * 136];
    __shared__ float g1s[32 * 132];
    const int t = threadIdx.x;
    const int row0 = blockIdx.x * 32;
    for (int i = t; i < 4096; i += 256)
        hus[(i >> 7) * 136 + (i & 127)] = hub[(size_t)row0 * 128 + i];
    __syncthreads();
    const int w = t >> 6, lane = t & 63;
    const int rt = w >> 1, half = w & 1;
    const int lrow = lane & 15, lkb = (lane >> 4) * 8;
    const int rloc = rt * 16 + (lane >> 4) * 4;
    bf16x8 a[4];
#pragma unroll
    for (int ks = 0; ks < 4; ++ks)
        a[ks] = *reinterpret_cast<const bf16x8*>(&hus[(rt * 16 + lrow) * 136 + ks * 32 + lkb]);
    // ---- stage 1: h_out = h + hu @ Wo + bo ----
    for (int ctp = 0; ctp < 4; ++ctp) {
        const int col = (ctp * 2 + half) * 16 + lrow;
        f32x4 acc = {0.f, 0.f, 0.f, 0.f};
#pragma unroll
        for (int ks = 0; ks < 4; ++ks) {
            bf16x8 b = *reinterpret_cast<const bf16x8*>(&Wt[3 * 16384 + col * 128 + ks * 32 + lkb]);
            acc = __builtin_amdgcn_mfma_f32_16x16x32_bf16(a[ks], b, acc, 0, 0, 0);
        }
        const float bias = bo[col];
#pragma unroll
        for (int r = 0; r < 4; ++r) {
            const int row = rloc + r;
            float hv = h[(size_t)(row0 + row) * 128 + col] + acc[r] + bias;
            hout[(size_t)(row0 + row) * 128 + col] = hv;
            hob[row * 136 + col] = f2bu(hv);
        }
    }
    __syncthreads();
    // ---- stage 2: g1 = silu(h_out @ Wg1 + bg1) ----
#pragma unroll
    for (int ks = 0; ks < 4; ++ks)
        a[ks] = *reinterpret_cast<const bf16x8*>(&hob[(rt * 16 + lrow) * 136 + ks * 32 + lkb]);
    for (int ctp = 0; ctp < 4; ++ctp) {
        const int col = (ctp * 2 + half) * 16 + lrow;
        f32x4 acc = {0.f, 0.f, 0.f, 0.f};
#pragma unroll
        for (int ks = 0; ks < 4; ++ks) {
            bf16x8 b = *reinterpret_cast<const bf16x8*>(&Wt[4 * 16384 + col * 128 + ks * 32 + lkb]);
            acc = __builtin_amdgcn_mfma_f32_16x16x32_bf16(a[ks], b, acc, 0, 0, 0);
        }
        const float bias = bg1[col];
#pragma unroll
        for (int r = 0; r < 4; ++r) {
            float av = acc[r] + bias;
            g1s[(rloc + r) * 132 + col] = av / (1.f + __expf(-av));
        }
    }
    __syncthreads();
    // ---- stage 3: gate = tanh(g1 @ wg2 + bg2); x_out ----
    {
        const int r = t >> 3, j = t & 7;
        float partial = 0.f;
        for (int cc = j; cc < 128; cc += 8) partial += g1s[r * 132 + cc] * wg2[cc];
        partial += __shfl_xor(partial, 1);
        partial += __shfl_xor(partial, 2);
        partial += __shfl_xor(partial, 4);
        const float gate = tanhf(partial + bg2[0]);
        if (j < 3) {
            const int row = row0 + r;
            xout[(size_t)row * 3 + j] = x[(size_t)row * 3 + j] + gate * disp[(size_t)row * 3 + j];
        }
    }
}

// ---------------------------------------------------------------- launcher

extern "C" void kernel_launch(void* const* d_in, const int* in_sizes, int n_in,
                              void* d_out, int out_size, void* d_ws, size_t ws_size,
                              hipStream_t stream) {
    const float* h     = (const float*)d_in[0];
    const float* x     = (const float*)d_in[1];
    const int*   src   = (const int*)d_in[2];
    const int*   dst   = (const int*)d_in[3];
    const float* dist  = (const float*)d_in[4];
    const float* bpp   = (const float*)d_in[5];
    const float* msa   = (const float*)d_in[6];
    const float* chem  = (const float*)d_in[7];
    const float* rel   = (const float*)d_in[8];
    const float* chain = (const float*)d_in[9];
    const float* Wq = (const float*)d_in[10];
    const float* Wk = (const float*)d_in[11];
    const float* Wv = (const float*)d_in[12];
    const float* Wo = (const float*)d_in[13];
    const float* bq = (const float*)d_in[14];
    const float* bk = (const float*)d_in[15];
    const float* bv = (const float*)d_in[16];
    const float* bo = (const float*)d_in[17];
    const float* w_dist = (const float*)d_in[18];  const float* b_dist = (const float*)d_in[19];
    const float* w_bpp  = (const float*)d_in[20];  const float* b_bpp  = (const float*)d_in[21];
    const float* w_msa  = (const float*)d_in[22];  const float* b_msa  = (const float*)d_in[23];
    const float* w_chem = (const float*)d_in[24];  const float* b_chem = (const float*)d_in[25];
    const float* w_rel  = (const float*)d_in[26];  const float* b_rel  = (const float*)d_in[27];
    const float* w_chain= (const float*)d_in[28];  const float* b_chain= (const float*)d_in[29];
    const float* Wg1 = (const float*)d_in[30];
    const float* bg1 = (const float*)d_in[31];
    const float* wg2 = (const float*)d_in[32];
    const float* bg2 = (const float*)d_in[33];

    char* wp = (char*)d_ws;
    const size_t NH2 = (size_t)N_NODES * HID * sizeof(ushort);   // 5,120,000
    ushort* hub   = (ushort*)wp;               wp += NH2;
    ushort* qb    = (ushort*)wp;               wp += NH2;
    ushort* kb    = (ushort*)wp;               wp += NH2;
    ushort* vb    = (ushort*)wp;               wp += NH2;
    uint4*  recs  = (uint4*)wp;                wp += (size_t)N_EDGES * 32;
    float*  disp  = (float*)wp;                wp += (size_t)N_NODES * 3 * sizeof(float);
    int* rank     = (int*)wp;                  wp += (size_t)N_EDGES * sizeof(int);
    int* startp   = (int*)wp;                  wp += (size_t)N_NODES * sizeof(int);
    int* cnt      = (int*)wp;                  wp += (size_t)N_NODES * sizeof(int);
    int* blockSums= (int*)wp;                  wp += (size_t)(NB_SCAN + 1) * sizeof(int);
    ushort* Wt    = (ushort*)wp;               wp += (size_t)5 * 16384 * sizeof(ushort);

    float* hout = (float*)d_out;
    float* xout = hout + (size_t)N_NODES * HID;

    hipMemsetAsync(cnt, 0, (size_t)N_NODES * sizeof(int), stream);
    hipLaunchKernelGGL(hist_prep_kernel, dim3(N_EDGES / 256 + PREP_BLOCKS), dim3(256), 0, stream,
                       src, cnt, rank, Wq, Wk, Wv, Wo, Wg1, Wt);
    hipLaunchKernelGGL(scan1_kernel, dim3(NB_SCAN), dim3(256), 0, stream,
                       cnt, startp, blockSums, N_NODES);
    hipLaunchKernelGGL(scan2_kernel, dim3(1), dim3(128), 0, stream, blockSums, NB_SCAN);
    hipLaunchKernelGGL(scatter_qkv_kernel, dim3(QKV_BLOCKS + N_EDGES / 256), dim3(256), 0, stream,
                       h, Wt, bq, bk, bv, qb, kb, vb,
                       src, dst, dist, bpp, msa, chem, rel, chain,
                       w_dist, b_dist, w_bpp, b_bpp, w_msa, b_msa,
                       w_chem, b_chem, w_rel, b_rel, w_chain, b_chain,
                       startp, blockSums, rank, x, recs);
    hipLaunchKernelGGL(node_kernel, dim3(N_NODES / 4), dim3(256), 0, stream,
                       qb, kb, vb, recs, x, startp, blockSums, hub, disp);
    hipLaunchKernelGGL(out_kernel, dim3(N_NODES / 32), dim3(256), 0, stream,
                       h, x, hub, Wt, bo, bg1, wg2, bg2, disp, hout, xout);
}

// Round 7
// 162.960 us; speedup vs baseline: 2.2156x; 1.0053x over previous
//
#include <hip/hip_runtime.h>
#include <hip/hip_bf16.h>

#define N_NODES 20000
#define N_EDGES 640000
#define HID 128
#define HEADS 8
#define HD 16
#define NB_SCAN ((N_NODES + 255) / 256)   // 79
#define CH 160                            // edges per chunk (covers 4-node union ~99.8%)
#define QKV_BLOCKS 625                    // 20000/32
#define PREP_BLOCKS 5

typedef __attribute__((ext_vector_type(8))) short bf16x8;
typedef __attribute__((ext_vector_type(4))) float f32x4;

__device__ __forceinline__ float bflo(unsigned u) {
    union { unsigned i; float f; } x; x.i = u << 16; return x.f;
}
__device__ __forceinline__ float bfhi(unsigned u) {
    union { unsigned i; float f; } x; x.i = u & 0xffff0000u; return x.f;
}
__device__ __forceinline__ float bfu(ushort u) {
    union { unsigned i; float f; } x; x.i = ((unsigned)u) << 16; return x.f;
}
__device__ __forceinline__ ushort f2bu(float f) {
    __hip_bfloat16 b = __float2bfloat16(f);
    union { __hip_bfloat16 b; ushort u; } c; c.b = b; return c.u;
}

// ------------------------------------------- fused prep (weights) + hist+rank
__global__ __launch_bounds__(256) void hist_prep_kernel(const int* __restrict__ src,
        int* __restrict__ cnt, int* __restrict__ rank,
        const float* __restrict__ Wq, const float* __restrict__ Wk,
        const float* __restrict__ Wv, const float* __restrict__ Wo,
        const float* __restrict__ Wg1, ushort* __restrict__ Wt) {
    if (blockIdx.x < PREP_BLOCKS) {
        const float* srcs[5] = {Wq, Wk, Wv, Wo, Wg1};
        const float* W = srcs[blockIdx.x];
        ushort* out = Wt + (size_t)blockIdx.x * 16384;
        for (int i = threadIdx.x; i < 16384; i += 256) {
            int k = i >> 7, n = i & 127;
            out[n * 128 + k] = f2bu(W[i]);
        }
    } else {
        const int e = (blockIdx.x - PREP_BLOCKS) * 256 + threadIdx.x;
        rank[e] = atomicAdd(&cnt[src[e]], 1);
    }
}

__global__ __launch_bounds__(256) void scan1_kernel(const int* __restrict__ cnt,
        int* __restrict__ startp, int* __restrict__ blockSums, int n) {
    __shared__ int sd[256];
    const int tid = threadIdx.x;
    const int i = blockIdx.x * 256 + tid;
    int xv = (i < n) ? cnt[i] : 0;
    sd[tid] = xv;
    __syncthreads();
#pragma unroll
    for (int off = 1; off < 256; off <<= 1) {
        int tv = (tid >= off) ? sd[tid - off] : 0;
        __syncthreads();
        sd[tid] += tv;
        __syncthreads();
    }
    if (i < n) startp[i] = sd[tid] - xv;
    if (tid == 255) blockSums[blockIdx.x] = sd[255];
}

__global__ __launch_bounds__(128) void scan2_kernel(int* __restrict__ blockSums, int nb) {
    __shared__ int sd[128];
    const int tid = threadIdx.x;
    int xv = (tid < nb) ? blockSums[tid] : 0;
    sd[tid] = xv;
    __syncthreads();
#pragma unroll
    for (int off = 1; off < 128; off <<= 1) {
        int tv = (tid >= off) ? sd[tid - off] : 0;
        __syncthreads();
        sd[tid] += tv;
        __syncthreads();
    }
    if (tid < nb) blockSums[tid] = sd[tid] - xv;
    if (tid == 127) blockSums[nb] = sd[127];
}

// ------------------- fused: qkv MFMA GEMM (blocks 0..624)  ∥  edge scatter
__global__ __launch_bounds__(256) void scatter_qkv_kernel(
        const float* __restrict__ h, const ushort* __restrict__ Wt,
        const float* __restrict__ bq, const float* __restrict__ bk,
        const float* __restrict__ bv,
        ushort* __restrict__ qb, ushort* __restrict__ kb, ushort* __restrict__ vb,
        const int* __restrict__ src, const int* __restrict__ dst,
        const float* __restrict__ dist, const float* __restrict__ bpp,
        const float* __restrict__ msa, const float* __restrict__ chem,
        const float* __restrict__ rel, const float* __restrict__ chain,
        const float* __restrict__ w_dist, const float* __restrict__ b_dist,
        const float* __restrict__ w_bpp, const float* __restrict__ b_bpp,
        const float* __restrict__ w_msa, const float* __restrict__ b_msa,
        const float* __restrict__ w_chem, const float* __restrict__ b_chem,
        const float* __restrict__ w_rel, const float* __restrict__ b_rel,
        const float* __restrict__ w_chain, const float* __restrict__ b_chain,
        const int* __restrict__ startp, const int* __restrict__ blockSums,
        const int* __restrict__ rank, const float* __restrict__ x,
        uint4* __restrict__ recs) {
    __shared__ __align__(16) ushort hs[32 * 136];
    const int t = threadIdx.x;
    if (blockIdx.x < QKV_BLOCKS) {
        const int row0 = blockIdx.x * 32;
        for (int i = t; i < 4096; i += 256)
            hs[(i >> 7) * 136 + (i & 127)] = f2bu(h[(size_t)row0 * 128 + i]);
        __syncthreads();
        const int w = t >> 6, lane = t & 63;
        const int rt = w >> 1, half = w & 1;
        const int lrow = lane & 15, lkb = (lane >> 4) * 8;
        bf16x8 a[4];
#pragma unroll
        for (int ks = 0; ks < 4; ++ks)
            a[ks] = *reinterpret_cast<const bf16x8*>(&hs[(rt * 16 + lrow) * 136 + ks * 32 + lkb]);
        __syncthreads();   // everyone done reading hs; reuse as output staging
        const int rloc0 = rt * 16 + (lane >> 4) * 4;
#define DO_MAT(MI, BIAS, OUT) \
        { \
        for (int ctp = 0; ctp < 4; ++ctp) { \
            const int col = (ctp * 2 + half) * 16 + lrow; \
            f32x4 acc = {0.f, 0.f, 0.f, 0.f}; \
            _Pragma("unroll") \
            for (int ks = 0; ks < 4; ++ks) { \
                bf16x8 b = *reinterpret_cast<const bf16x8*>( \
                    &Wt[MI * 16384 + col * 128 + ks * 32 + lkb]); \
                acc = __builtin_amdgcn_mfma_f32_16x16x32_bf16(a[ks], b, acc, 0, 0, 0); \
            } \
            const float bias = BIAS[col]; \
            _Pragma("unroll") \
            for (int r = 0; r < 4; ++r) \
                hs[(rloc0 + r) * 128 + col] = f2bu(acc[r] + bias); \
        } \
        __syncthreads(); \
        { \
            uint4* outp = reinterpret_cast<uint4*>(OUT + (size_t)row0 * 128); \
            const uint4* inp = reinterpret_cast<const uint4*>(hs); \
            outp[t] = inp[t]; \
            outp[t + 256] = inp[t + 256]; \
        } \
        __syncthreads(); \
        }
        DO_MAT(0, bq, qb)
        DO_MAT(1, bk, kb)
        DO_MAT(2, bv, vb)
#undef DO_MAT
    } else {
        const int e = (blockIdx.x - QKV_BLOCKS) * 256 + t;
        const int s = src[e];
        const int pos = startp[s] + blockSums[s >> 8] + rank[e];
        const int dn = dst[e];
        const float d2 = dist[e] * dist[e];
        const float f_bpp = bpp[e], f_msa = msa[e], f_chem = chem[e];
        const float f_rel = rel[e], f_chain = chain[e];
        ushort o16[8];
#pragma unroll
        for (int hq = 0; hq < 8; ++hq) {
            float b = -(d2 * w_dist[hq] + b_dist[hq])
                    + (f_bpp * w_bpp[hq] + b_bpp[hq])
                    + (f_msa * w_msa[hq] + b_msa[hq])
                    + (f_chem * w_chem[hq] + b_chem[hq])
                    + (f_rel * w_rel[hq] + b_rel[hq])
                    + (f_chain * w_chain[hq] + b_chain[hq]);
            o16[hq] = f2bu(b);
        }
        uint4 rec0;
        rec0.x = (unsigned)o16[0] | ((unsigned)o16[1] << 16);
        rec0.y = (unsigned)o16[2] | ((unsigned)o16[3] << 16);
        rec0.z = (unsigned)o16[4] | ((unsigned)o16[5] << 16);
        rec0.w = (unsigned)o16[6] | ((unsigned)o16[7] << 16);
        const float* xp = &x[(size_t)dn * 3];
        uint4 rec1;
        rec1.x = (unsigned)dn;
        rec1.y = __float_as_uint(xp[0]);
        rec1.z = __float_as_uint(xp[1]);
        rec1.w = __float_as_uint(xp[2]);
        recs[(size_t)pos * 2]     = rec0;
        recs[(size_t)pos * 2 + 1] = rec1;
    }
}

// --------------------------------------------- per-node fused softmax + agg
__global__ __launch_bounds__(256) void node_kernel(const ushort* __restrict__ qb,
        const ushort* __restrict__ kb, const ushort* __restrict__ vb,
        const uint4* __restrict__ recs, const float* __restrict__ x,
        const int* __restrict__ startp, const int* __restrict__ blockSums,
        ushort* __restrict__ hub, float* __restrict__ disp) {
    __shared__ float qLds[4 * 128];
    __shared__ float xsLds[12];
    __shared__ int   sLds[5];
    __shared__ int   dnLds[CH];
    __shared__ float xLds[CH * 3];
    __shared__ __align__(16) ushort biasLds[CH * 8];
    __shared__ float peLds[CH * 8];
    __shared__ float redN[4][32][9];

    const int t = threadIdx.x;
    const int n0 = blockIdx.x * 4;

    if (t < 64) {
        uint4 qv = reinterpret_cast<const uint4*>(qb + (size_t)n0 * 128)[t];
        const unsigned* qu = reinterpret_cast<const unsigned*>(&qv);
        float4 f0 = make_float4(bflo(qu[0]), bfhi(qu[0]), bflo(qu[1]), bfhi(qu[1]));
        float4 f1 = make_float4(bflo(qu[2]), bfhi(qu[2]), bflo(qu[3]), bfhi(qu[3]));
        *reinterpret_cast<float4*>(&qLds[t * 8])     = f0;
        *reinterpret_cast<float4*>(&qLds[t * 8 + 4]) = f1;
    }
    if (t < 12) xsLds[t] = x[(size_t)n0 * 3 + t];
    if (t < 5) {
        int idx = n0 + t;
        sLds[t] = (idx < N_NODES) ? (startp[idx] + blockSums[idx >> 8]) : N_EDGES;
    }
    __syncthreads();

    const int S0 = sLds[0], S4 = sLds[4];
    const int s1r = sLds[1], s2r = sLds[2], s3r = sLds[3];

    const int eg = t >> 5;          // 0..7 edge-group
    const int dq = t & 31;          // dim-quad: dims 4dq..4dq+3
    const int hh = dq >> 2;         // head
    const int jj = dq & 3;
    const int j3 = (jj < 3) ? jj : 0;

    float acc0[4] = {0,0,0,0}, acc1[4] = {0,0,0,0};
    float acc2[4] = {0,0,0,0}, acc3[4] = {0,0,0,0};
    float den0 = 0, den1 = 0, den2 = 0, den3 = 0;
    float adx0 = 0, adx1 = 0, adx2 = 0, adx3 = 0;

    for (int base = S0; base < S4; base += CH) {
        const int en = min(CH, S4 - base);
        __syncthreads();
        if (t < en) {
            const uint4 r0 = recs[(size_t)(base + t) * 2];
            const uint4 r1 = recs[(size_t)(base + t) * 2 + 1];
            *reinterpret_cast<uint4*>(&biasLds[t * 8]) = r0;
            dnLds[t] = (int)r1.x;
            xLds[t * 3 + 0] = __uint_as_float(r1.y);
            xLds[t * 3 + 1] = __uint_as_float(r1.z);
            xLds[t * 3 + 2] = __uint_as_float(r1.w);
        }
        __syncthreads();
        // ---- phase A: exp-logits, 4 partial sums + 2x unroll ----
        const int np = en * 8;
#define PA_BODY(P) { \
            const int e = (P) >> 3, ha = (P) & 7; \
            const int ge = base + e; \
            const int m = (ge >= s1r) + (ge >= s2r) + (ge >= s3r); \
            const ushort* krow = kb + (size_t)dnLds[e] * 128 + ha * 16; \
            const uint4 ka = *reinterpret_cast<const uint4*>(krow); \
            const uint4 kb4 = *reinterpret_cast<const uint4*>(krow + 8); \
            const float* qrow = &qLds[m * 128 + ha * 16]; \
            const unsigned* kau = reinterpret_cast<const unsigned*>(&ka); \
            const unsigned* kbu = reinterpret_cast<const unsigned*>(&kb4); \
            float s0 = 0.f, s1 = 0.f, s2 = 0.f, s3 = 0.f; \
            _Pragma("unroll") \
            for (int i = 0; i < 4; ++i) { \
                s0 = fmaf(bflo(kau[i]), qrow[2 * i],     s0); \
                s1 = fmaf(bfhi(kau[i]), qrow[2 * i + 1], s1); \
                s2 = fmaf(bflo(kbu[i]), qrow[8 + 2 * i],     s2); \
                s3 = fmaf(bfhi(kbu[i]), qrow[8 + 2 * i + 1], s3); \
            } \
            peLds[P] = __expf(fmaf((s0 + s1) + (s2 + s3), 0.25f, bfu(biasLds[P]))); \
        }
        {
            int p = t;
            for (; p + 256 < np; p += 512) { PA_BODY(p) PA_BODY(p + 256) }
            if (p < np) PA_BODY(p)
        }
#undef PA_BODY
        __syncthreads();
        // ---- phase C: per-node gather-accumulate, 2x unroll ----
#define PC_BODY(E, ACC, DEN, ADX, XSV) { \
            const float pe = peLds[(E) * 8 + hh]; \
            const ushort4 vv = *reinterpret_cast<const ushort4*>( \
                vb + (size_t)dnLds[E] * 128 + dq * 4); \
            ACC[0] = fmaf(pe, bfu(vv.x), ACC[0]); \
            ACC[1] = fmaf(pe, bfu(vv.y), ACC[1]); \
            ACC[2] = fmaf(pe, bfu(vv.z), ACC[2]); \
            ACC[3] = fmaf(pe, bfu(vv.w), ACC[3]); \
            DEN += pe; \
            ADX = fmaf(pe, xLds[(E) * 3 + j3] - XSV, ADX); \
        }
#define NODE_C(M, ACC, DEN, ADX) { \
            const int lo = max(sLds[M] - base, 0); \
            const int hi = min(sLds[M + 1] - base, en); \
            const float xsv = xsLds[M * 3 + j3]; \
            int e = lo + eg; \
            for (; e + 8 < hi; e += 16) { \
                PC_BODY(e, ACC, DEN, ADX, xsv) \
                PC_BODY(e + 8, ACC, DEN, ADX, xsv) \
            } \
            if (e < hi) PC_BODY(e, ACC, DEN, ADX, xsv) \
        }
        NODE_C(0, acc0, den0, adx0)
        NODE_C(1, acc1, den1, adx1)
        NODE_C(2, acc2, den2, adx2)
        NODE_C(3, acc3, den3, adx3)
#undef NODE_C
#undef PC_BODY
    }

    // ---- epilogue: shfl pre-reduce over eg pairs, light LDS reduce ----
    const int wv = t >> 6, lane = t & 63;
#define RED_M(M, ACC, DEN, ADX) { \
        float r0 = ACC[0], r1 = ACC[1], r2 = ACC[2], r3 = ACC[3]; \
        float rd = DEN, rx = (jj < 3) ? ADX : 0.f; \
        r0 += __shfl_xor(r0, 32); r1 += __shfl_xor(r1, 32); \
        r2 += __shfl_xor(r2, 32); r3 += __shfl_xor(r3, 32); \
        rd += __shfl_xor(rd, 32); rx += __shfl_xor(rx, 32); \
        if (lane < 32) { \
            redN[wv][lane][0] = r0; redN[wv][lane][1] = r1; \
            redN[wv][lane][2] = r2; redN[wv][lane][3] = r3; \
            redN[wv][lane][4] = rd; redN[wv][lane][5] = rx; \
        } \
        __syncthreads(); \
        if (t < 128) { \
            const int dqr = t >> 2, vi = t & 3; \
            float s = redN[0][dqr][vi] + redN[1][dqr][vi] \
                    + redN[2][dqr][vi] + redN[3][dqr][vi]; \
            float d = redN[0][dqr][4] + redN[1][dqr][4] \
                    + redN[2][dqr][4] + redN[3][dqr][4]; \
            hub[(size_t)(n0 + M) * 128 + t] = f2bu(s / fmaxf(d, 1e-9f)); \
        } \
        if (t < 32) { \
            float v = redN[0][t][5] + redN[1][t][5] + redN[2][t][5] + redN[3][t][5]; \
            float d = redN[0][t][4] + redN[1][t][4] + redN[2][t][4] + redN[3][t][4]; \
            float s = v / fmaxf(d, 1e-9f); \
            s += __shfl_xor(s, 4); s += __shfl_xor(s, 8); s += __shfl_xor(s, 16); \
            if (t < 3) disp[(size_t)(n0 + M) * 3 + t] = s * 0.125f; \
        } \
        __syncthreads(); }
    RED_M(0, acc0, den0, adx0)
    RED_M(1, acc1, den1, adx1)
    RED_M(2, acc2, den2, adx2)
    RED_M(3, acc3, den3, adx3)
#undef RED_M
}

// --------------------- fused output GEMM + gate MLP + coords (MFMA)
__global__ __launch_bounds__(256) void out_kernel(const float* __restrict__ h,
        const float* __restrict__ x, const ushort* __restrict__ hub,
        const ushort* __restrict__ Wt,
        const float* __restrict__ bo, const float* __restrict__ bg1,
        const float* __restrict__ wg2, const float* __restrict__ bg2,
        const float* __restrict__ disp,
        float* __restrict__ hout, float* __restrict__ xout) {
    __shared__ __align__(16) ushort hus[32 * 136];
    __shared__ __align__(16) float hof[32 * 132];   // fp32 h_out tile
    __shared__ float g1s[32 * 132];
    const int t = threadIdx.x;
    const int row0 = blockIdx.x * 32;
    // stage hu tile (bf16, coalesced uint4) and h tile (fp32, coalesced float4)
    for (int i8 = t; i8 < 512; i8 += 256) {
        const int row = i8 >> 4, c8 = (i8 & 15) * 8;
        *reinterpret_cast<uint4*>(&hus[row * 136 + c8]) =
            reinterpret_cast<const uint4*>(hub + (size_t)row0 * 128)[i8];
    }
    for (int i4 = t; i4 < 1024; i4 += 256) {
        const int row = i4 >> 5, c4 = (i4 & 31) * 4;
        *reinterpret_cast<float4*>(&hof[row * 132 + c4]) =
            reinterpret_cast<const float4*>(h + (size_t)row0 * 128)[i4];
    }
    __syncthreads();
    const int w = t >> 6, lane = t & 63;
    const int rt = w >> 1, half = w & 1;
    const int lrow = lane & 15, lkb = (lane >> 4) * 8;
    const int rloc = rt * 16 + (lane >> 4) * 4;
    bf16x8 a[4];
#pragma unroll
    for (int ks = 0; ks < 4; ++ks)
        a[ks] = *reinterpret_cast<const bf16x8*>(&hus[(rt * 16 + lrow) * 136 + ks * 32 + lkb]);
    // ---- stage 1: hof += hu @ Wo + bo  (h already staged in hof) ----
    for (int ctp = 0; ctp < 4; ++ctp) {
        const int col = (ctp * 2 + half) * 16 + lrow;
        f32x4 acc = {0.f, 0.f, 0.f, 0.f};
#pragma unroll
        for (int ks = 0; ks < 4; ++ks) {
            bf16x8 b = *reinterpret_cast<const bf16x8*>(&Wt[3 * 16384 + col * 128 + ks * 32 + lkb]);
            acc = __builtin_amdgcn_mfma_f32_16x16x32_bf16(a[ks], b, acc, 0, 0, 0);
        }
        const float bias = bo[col];
#pragma unroll
        for (int r = 0; r < 4; ++r)
            hof[(rloc + r) * 132 + col] += acc[r] + bias;
    }
    __syncthreads();
    // dump h_out coalesced + build stage-2 A-frags from hof
    for (int i4 = t; i4 < 1024; i4 += 256) {
        const int row = i4 >> 5, c4 = (i4 & 31) * 4;
        *reinterpret_cast<float4*>(hout + (size_t)(row0 + row) * 128 + c4) =
            *reinterpret_cast<const float4*>(&hof[row * 132 + c4]);
    }
    bf16x8 a2[4];
#pragma unroll
    for (int ks = 0; ks < 4; ++ks) {
        const float* fp = &hof[(rt * 16 + lrow) * 132 + ks * 32 + lkb];
        const float4 f0 = *reinterpret_cast<const float4*>(fp);
        const float4 f1 = *reinterpret_cast<const float4*>(fp + 4);
        bf16x8 v;
        v[0] = (short)f2bu(f0.x); v[1] = (short)f2bu(f0.y);
        v[2] = (short)f2bu(f0.z); v[3] = (short)f2bu(f0.w);
        v[4] = (short)f2bu(f1.x); v[5] = (short)f2bu(f1.y);
        v[6] = (short)f2bu(f1.z); v[7] = (short)f2bu(f1.w);
        a2[ks] = v;
    }
    // ---- stage 2: g1 = silu(h_out @ Wg1 + bg1) ----
    for (int ctp = 0; ctp < 4; ++ctp) {
        const int col = (ctp * 2 + half) * 16 + lrow;
        f32x4 acc = {0.f, 0.f, 0.f, 0.f};
#pragma unroll
        for (int ks = 0; ks < 4; ++ks) {
            bf16x8 b = *reinterpret_cast<const bf16x8*>(&Wt[4 * 16384 + col * 128 + ks * 32 + lkb]);
            acc = __builtin_amdgcn_mfma_f32_16x16x32_bf16(a2[ks], b, acc, 0, 0, 0);
        }
        const float bias = bg1[col];
#pragma unroll
        for (int r = 0; r < 4; ++r) {
            float av = acc[r] + bias;
            g1s[(rloc + r) * 132 + col] = av / (1.f + __expf(-av));
        }
    }
    __syncthreads();
    // ---- stage 3: gate = tanh(g1 @ wg2 + bg2); x_out ----
    {
        const int r = t >> 3, j = t & 7;
        float partial = 0.f;
        for (int cc = j; cc < 128; cc += 8) partial += g1s[r * 132 + cc] * wg2[cc];
        partial += __shfl_xor(partial, 1);
        partial += __shfl_xor(partial, 2);
        partial += __shfl_xor(partial, 4);
        const float gate = tanhf(partial + bg2[0]);
        if (j < 3) {
            const int row = row0 + r;
            xout[(size_t)row * 3 + j] = x[(size_t)row * 3 + j] + gate * disp[(size_t)row * 3 + j];
        }
    }
}

// ---------------------------------------------------------------- launcher

extern "C" void kernel_launch(void* const* d_in, const int* in_sizes, int n_in,
                              void* d_out, int out_size, void* d_ws, size_t ws_size,
                              hipStream_t stream) {
    const float* h     = (const float*)d_in[0];
    const float* x     = (const float*)d_in[1];
    const int*   src   = (const int*)d_in[2];
    const int*   dst   = (const int*)d_in[3];
    const float* dist  = (const float*)d_in[4];
    const float* bpp   = (const float*)d_in[5];
    const float* msa   = (const float*)d_in[6];
    const float* chem  = (const float*)d_in[7];
    const float* rel   = (const float*)d_in[8];
    const float* chain = (const float*)d_in[9];
    const float* Wq = (const float*)d_in[10];
    const float* Wk = (const float*)d_in[11];
    const float* Wv = (const float*)d_in[12];
    const float* Wo = (const float*)d_in[13];
    const float* bq = (const float*)d_in[14];
    const float* bk = (const float*)d_in[15];
    const float* bv = (const float*)d_in[16];
    const float* bo = (const float*)d_in[17];
    const float* w_dist = (const float*)d_in[18];  const float* b_dist = (const float*)d_in[19];
    const float* w_bpp  = (const float*)d_in[20];  const float* b_bpp  = (const float*)d_in[21];
    const float* w_msa  = (const float*)d_in[22];  const float* b_msa  = (const float*)d_in[23];
    const float* w_chem = (const float*)d_in[24];  const float* b_chem = (const float*)d_in[25];
    const float* w_rel  = (const float*)d_in[26];  const float* b_rel  = (const float*)d_in[27];
    const float* w_chain= (const float*)d_in[28];  const float* b_chain= (const float*)d_in[29];
    const float* Wg1 = (const float*)d_in[30];
    const float* bg1 = (const float*)d_in[31];
    const float* wg2 = (const float*)d_in[32];
    const float* bg2 = (const float*)d_in[33];

    char* wp = (char*)d_ws;
    const size_t NH2 = (size_t)N_NODES * HID * sizeof(ushort);   // 5,120,000
    ushort* hub   = (ushort*)wp;               wp += NH2;
    ushort* qb    = (ushort*)wp;               wp += NH2;
    ushort* kb    = (ushort*)wp;               wp += NH2;
    ushort* vb    = (ushort*)wp;               wp += NH2;
    uint4*  recs  = (uint4*)wp;                wp += (size_t)N_EDGES * 32;
    float*  disp  = (float*)wp;                wp += (size_t)N_NODES * 3 * sizeof(float);
    int* rank     = (int*)wp;                  wp += (size_t)N_EDGES * sizeof(int);
    int* startp   = (int*)wp;                  wp += (size_t)N_NODES * sizeof(int);
    int* cnt      = (int*)wp;                  wp += (size_t)N_NODES * sizeof(int);
    int* blockSums= (int*)wp;                  wp += (size_t)(NB_SCAN + 1) * sizeof(int);
    ushort* Wt    = (ushort*)wp;               wp += (size_t)5 * 16384 * sizeof(ushort);

    float* hout = (float*)d_out;
    float* xout = hout + (size_t)N_NODES * HID;

    hipMemsetAsync(cnt, 0, (size_t)N_NODES * sizeof(int), stream);
    hipLaunchKernelGGL(hist_prep_kernel, dim3(N_EDGES / 256 + PREP_BLOCKS), dim3(256), 0, stream,
                       src, cnt, rank, Wq, Wk, Wv, Wo, Wg1, Wt);
    hipLaunchKernelGGL(scan1_kernel, dim3(NB_SCAN), dim3(256), 0, stream,
                       cnt, startp, blockSums, N_NODES);
    hipLaunchKernelGGL(scan2_kernel, dim3(1), dim3(128), 0, stream, blockSums, NB_SCAN);
    hipLaunchKernelGGL(scatter_qkv_kernel, dim3(QKV_BLOCKS + N_EDGES / 256), dim3(256), 0, stream,
                       h, Wt, bq, bk, bv, qb, kb, vb,
                       src, dst, dist, bpp, msa, chem, rel, chain,
                       w_dist, b_dist, w_bpp, b_bpp, w_msa, b_msa,
                       w_chem, b_chem, w_rel, b_rel, w_chain, b_chain,
                       startp, blockSums, rank, x, recs);
    hipLaunchKernelGGL(node_kernel, dim3(N_NODES / 4), dim3(256), 0, stream,
                       qb, kb, vb, recs, x, startp, blockSums, hub, disp);
    hipLaunchKernelGGL(out_kernel, dim3(N_NODES / 32), dim3(256), 0, stream,
                       h, x, hub, Wt, bo, bg1, wg2, bg2, disp, hout, xout);
}